// Round 1
// baseline (2038.517 us; speedup 1.0000x reference)
//
#include <hip/hip_runtime.h>
#include <hip/hip_bf16.h>

#define NUM_NODE 40000
#define DIM 100
#define NBATCH 128
#define NSEQ 70
#define NEDGE 640000
#define LEAKY_ALPHA 0.2f
#define RPB 35   // intra rows per block (2 blocks per batch)

// ---------------- SpMM: y[rows[e]] += vals[e] * x[cols[e]]  ----------------
// 25 threads per edge, each handling a float4 chunk of DIM=100.
__global__ __launch_bounds__(256) void spmm_kernel(
    const int* __restrict__ rows, const int* __restrict__ cols,
    const float* __restrict__ vals, const float* __restrict__ x,
    float* __restrict__ y)
{
    int gid = blockIdx.x * 256 + threadIdx.x;   // total = NEDGE*25 = 16,000,000
    int e = gid / 25;
    int c = gid - e * 25;
    if (e >= NEDGE) return;
    int r = rows[e], cl = cols[e];
    float v = vals[e];
    const float4 xv = *reinterpret_cast<const float4*>(x + (size_t)cl * DIM + c * 4);
    float* yp = y + (size_t)r * DIM + c * 4;
    unsafeAtomicAdd(yp + 0, v * xv.x);
    unsafeAtomicAdd(yp + 1, v * xv.y);
    unsafeAtomicAdd(yp + 2, v * xv.z);
    unsafeAtomicAdd(yp + 3, v * xv.w);
}

// ---------------- session: s[b,d] = (1/len) * sum_n emb_pad[sess_item[b,n], d] ----
__global__ void sess_sum_kernel(const int* __restrict__ sess_item,
                                const float* __restrict__ emb,
                                const float* __restrict__ sess_len,
                                float* __restrict__ s)
{
    int b = blockIdx.x, d = threadIdx.x;
    if (d >= DIM) return;
    float acc = 0.f;
    for (int n = 0; n < NSEQ; ++n) {
        int r = sess_item[b * NSEQ + n];
        if (r > 0) acc += emb[(size_t)(r - 1) * DIM + d];
    }
    s[b * DIM + d] = acc / sess_len[b];
}

// ---------------- DA = D @ A  (128x128) ----------------
__global__ void da_kernel(const float* __restrict__ Dm, const float* __restrict__ Am,
                          float* __restrict__ DA)
{
    int i = blockIdx.x, j = threadIdx.x;
    float acc = 0.f;
    for (int k = 0; k < NBATCH; ++k) acc += Dm[i * NBATCH + k] * Am[k * NBATCH + j];
    DA[i * NBATCH + j] = acc;
}

// ---------------- sout = DA @ sin  ([B,B]@[B,D]) ----------------
__global__ void sprop_kernel(const float* __restrict__ DA, const float* __restrict__ sin_,
                             float* __restrict__ sout)
{
    int i = blockIdx.x, d = threadIdx.x;
    if (d >= DIM) return;
    float acc = 0.f;
    for (int k = 0; k < NBATCH; ++k) acc += DA[i * NBATCH + k] * sin_[k * DIM + d];
    sout[i * DIM + d] = acc;
}

__global__ void sess_final_kernel(const float* __restrict__ s, const float* __restrict__ s1,
                                  const float* __restrict__ s2, float* __restrict__ out2)
{
    int i = blockIdx.x, d = threadIdx.x;
    if (d >= DIM) return;
    int o = i * DIM + d;
    out2[o] = (s[o] + s1[o] + s2[o]) * (1.f / 3.f);
}

// ---------------- intra attention + final combine ----------------
// blockIdx.x = b*2 + half; rows i in [half*RPB, half*RPB+RPB)
__global__ __launch_bounds__(256) void intra_kernel(
    const int* __restrict__ inputs, const int* __restrict__ edge,
    const int* __restrict__ sess_item,
    const float* __restrict__ emb, const float* __restrict__ y1,
    const float* __restrict__ y2,
    const float* __restrict__ a0, const float* __restrict__ a1,
    const float* __restrict__ a2, const float* __restrict__ a3,
    float* __restrict__ out)
{
    __shared__ float h[NSEQ][DIM + 1];   // stride 101 (odd) -> bank-friendly
    __shared__ float al[RPB][NSEQ];
    __shared__ float av[4][DIM];
    int b = blockIdx.x >> 1;
    int half = blockIdx.x & 1;
    int tid = threadIdx.x;

    for (int idx = tid; idx < NSEQ * DIM; idx += 256) {
        int n = idx / DIM, d = idx - n * DIM;
        h[n][d] = emb[(size_t)inputs[b * NSEQ + n] * DIM + d];
    }
    for (int idx = tid; idx < 4 * DIM; idx += 256) {
        int k = idx / DIM, d = idx - k * DIM;
        const float* ap = (k == 0) ? a0 : (k == 1) ? a1 : (k == 2) ? a2 : a3;
        av[k][d] = ap[d];
    }
    __syncthreads();

    // phase A: selected logits. adjacency value picks ONE of the 4 e_k.
    for (int p = tid; p < RPB * NSEQ; p += 256) {
        int il = p / NSEQ, j = p - il * NSEQ;
        int i = half * RPB + il;
        int em = edge[(size_t)b * NSEQ * NSEQ + i * NSEQ + j];
        float val = -9e15f;
        if (em >= 1 && em <= 4) {
            const float* a = av[em - 1];
            float sdot = 0.f;
            #pragma unroll 4
            for (int d = 0; d < DIM; ++d) sdot += h[i][d] * h[j][d] * a[d];
            val = sdot >= 0.f ? sdot : LEAKY_ALPHA * sdot;
        }
        al[il][j] = val;
    }
    __syncthreads();

    // phase B: row softmax (serial per row; 35 rows, tiny)
    if (tid < RPB) {
        float m = -INFINITY;
        for (int j = 0; j < NSEQ; ++j) m = fmaxf(m, al[tid][j]);
        float ssum = 0.f;
        for (int j = 0; j < NSEQ; ++j) {
            float ex = __expf(al[tid][j] - m);
            al[tid][j] = ex;
            ssum += ex;
        }
        float inv = 1.f / ssum;
        for (int j = 0; j < NSEQ; ++j) al[tid][j] *= inv;
    }
    __syncthreads();

    // phase C: out[b,i,d] = sum_j alpha[i,j]*h[j,d] + inter_pad[sess_item[b,i], d]
    for (int p = tid; p < RPB * DIM; p += 256) {
        int il = p / DIM, d = p - il * DIM;
        int i = half * RPB + il;
        float acc = 0.f;
        #pragma unroll 5
        for (int j = 0; j < NSEQ; ++j) acc += al[il][j] * h[j][d];
        int r = sess_item[b * NSEQ + i];
        if (r > 0) {
            size_t o = (size_t)(r - 1) * DIM + d;
            acc += (emb[o] + y1[o] + y2[o]) * (1.f / 3.f);
        }
        out[(size_t)b * NSEQ * DIM + (size_t)i * DIM + d] = acc;
    }
}

extern "C" void kernel_launch(void* const* d_in, const int* in_sizes, int n_in,
                              void* d_out, int out_size, void* d_ws, size_t ws_size,
                              hipStream_t stream) {
    const int*   inputs    = (const int*)d_in[0];
    const int*   edge      = (const int*)d_in[1];
    // d_in[2] mask: unused; d_in[3] reversed_sess_item: unused
    const int*   sess_item = (const int*)d_in[4];
    const float* Dm        = (const float*)d_in[5];
    const float* Am        = (const float*)d_in[6];
    const float* sess_len  = (const float*)d_in[7];
    const float* emb       = (const float*)d_in[8];
    const float* a0        = (const float*)d_in[9];
    const float* a1        = (const float*)d_in[10];
    const float* a2        = (const float*)d_in[11];
    const float* a3        = (const float*)d_in[12];
    const int*   arows     = (const int*)d_in[13];
    const int*   acols     = (const int*)d_in[14];
    const float* avals     = (const float*)d_in[15];

    float* out      = (float*)d_out;                    // [B,N,D] = 896000
    float* out_sess = out + (size_t)NBATCH * NSEQ * DIM; // [B,D]   = 12800

    const size_t MAT = (size_t)NUM_NODE * DIM * sizeof(float);   // 16,000,000 B
    char* ws = (char*)d_ws;
    float* y1 = (float*)ws;
    float* y2 = (float*)(ws + MAT);
    float* s  = (float*)(ws + 2 * MAT);
    float* DA = (float*)(ws + 2 * MAT + 64 * 1024);
    float* s1 = (float*)(ws + 2 * MAT + 2 * 64 * 1024);
    float* s2 = (float*)(ws + 2 * MAT + 3 * 64 * 1024);

    // zero both SpMM accumulators
    hipMemsetAsync(y1, 0, 2 * MAT, stream);

    // inter: two propagation layers
    const int spmm_blocks = (NEDGE * 25) / 256;  // 62500 exactly
    spmm_kernel<<<spmm_blocks, 256, 0, stream>>>(arows, acols, avals, emb, y1);
    spmm_kernel<<<spmm_blocks, 256, 0, stream>>>(arows, acols, avals, y1, y2);

    // session chain
    sess_sum_kernel<<<NBATCH, 128, 0, stream>>>(sess_item, emb, sess_len, s);
    da_kernel<<<NBATCH, NBATCH, 0, stream>>>(Dm, Am, DA);
    sprop_kernel<<<NBATCH, 128, 0, stream>>>(DA, s, s1);
    sprop_kernel<<<NBATCH, 128, 0, stream>>>(DA, s1, s2);
    sess_final_kernel<<<NBATCH, 128, 0, stream>>>(s, s1, s2, out_sess);

    // intra attention + fused inter-gather + final add
    intra_kernel<<<NBATCH * 2, 256, 0, stream>>>(inputs, edge, sess_item,
                                                 emb, y1, y2, a0, a1, a2, a3, out);
}

// Round 2
// 325.397 us; speedup vs baseline: 6.2647x; 6.2647x over previous
//
#include <hip/hip_runtime.h>
#include <hip/hip_bf16.h>

#define NUM_NODE 40000
#define DIM 100
#define NBATCH 128
#define NSEQ 70
#define NEDGE 640000
#define LEAKY_ALPHA 0.2f
#define RPB 35   // intra rows per block (2 blocks per batch)

// ---------------- CSR build: histogram ----------------
__global__ __launch_bounds__(256) void hist_kernel(const int* __restrict__ rows,
                                                   int* __restrict__ cnt)
{
    int gid = blockIdx.x * 256 + threadIdx.x;
    if (gid < NEDGE) atomicAdd(&cnt[rows[gid]], 1);
}

// ---------------- CSR build: exclusive prefix scan (single block) ----------------
__global__ __launch_bounds__(1024) void scan_kernel(const int* __restrict__ cnt,
                                                    int* __restrict__ row_start)
{
    __shared__ int s[1024];
    int tid = threadIdx.x;
    int base = 0;
    const int nchunk = (NUM_NODE + 1023) / 1024;
    for (int c = 0; c < nchunk; ++c) {
        int i = c * 1024 + tid;
        int v = (i < NUM_NODE) ? cnt[i] : 0;
        s[tid] = v;
        __syncthreads();
        for (int off = 1; off < 1024; off <<= 1) {
            int t = (tid >= off) ? s[tid - off] : 0;
            __syncthreads();
            s[tid] += t;
            __syncthreads();
        }
        if (i < NUM_NODE) row_start[i] = base + s[tid] - v;  // exclusive
        base += s[1023];
        __syncthreads();
    }
}

// ---------------- CSR build: scatter (mutates row_start -> becomes row END) ----
__global__ __launch_bounds__(256) void scatter_kernel(
    const int* __restrict__ rows, const int* __restrict__ cols,
    const float* __restrict__ vals, int* __restrict__ row_start,
    int2* __restrict__ edge_data)
{
    int gid = blockIdx.x * 256 + threadIdx.x;
    if (gid >= NEDGE) return;
    int r = rows[gid];
    int pos = atomicAdd(&row_start[r], 1);
    edge_data[pos] = make_int2(cols[gid], __float_as_int(vals[gid]));
}

// ---------------- CSR SpMM: y[r] = sum_e val[e] * x[col[e]]  (no atomics) ------
// After scatter: row r spans [ (r?row_start[r-1]:0), row_start[r] ).
// 25 threads per row, one float4 chunk each.
__global__ __launch_bounds__(256) void csr_spmm_kernel(
    const int* __restrict__ row_start, const int2* __restrict__ edge_data,
    const float* __restrict__ x, float* __restrict__ y)
{
    int gid = blockIdx.x * 256 + threadIdx.x;   // NUM_NODE*25 = 1,000,000
    int r = gid / 25;
    int c = gid - r * 25;
    if (r >= NUM_NODE) return;
    int s0 = (r > 0) ? row_start[r - 1] : 0;
    int s1 = row_start[r];
    float4 acc = make_float4(0.f, 0.f, 0.f, 0.f);
    for (int e = s0; e < s1; ++e) {
        int2 ed = edge_data[e];
        float v = __int_as_float(ed.y);
        const float4 xv = *reinterpret_cast<const float4*>(x + (size_t)ed.x * DIM + c * 4);
        acc.x += v * xv.x;
        acc.y += v * xv.y;
        acc.z += v * xv.z;
        acc.w += v * xv.w;
    }
    *reinterpret_cast<float4*>(y + (size_t)r * DIM + c * 4) = acc;
}

// ---------------- session: s[b,d] = (1/len) * sum_n emb_pad[sess_item[b,n], d] ----
__global__ void sess_sum_kernel(const int* __restrict__ sess_item,
                                const float* __restrict__ emb,
                                const float* __restrict__ sess_len,
                                float* __restrict__ s)
{
    int b = blockIdx.x, d = threadIdx.x;
    if (d >= DIM) return;
    float acc = 0.f;
    for (int n = 0; n < NSEQ; ++n) {
        int r = sess_item[b * NSEQ + n];
        if (r > 0) acc += emb[(size_t)(r - 1) * DIM + d];
    }
    s[b * DIM + d] = acc / sess_len[b];
}

// ---------------- DA = D @ A  (128x128) ----------------
__global__ void da_kernel(const float* __restrict__ Dm, const float* __restrict__ Am,
                          float* __restrict__ DA)
{
    int i = blockIdx.x, j = threadIdx.x;
    float acc = 0.f;
    for (int k = 0; k < NBATCH; ++k) acc += Dm[i * NBATCH + k] * Am[k * NBATCH + j];
    DA[i * NBATCH + j] = acc;
}

// ---------------- sout = DA @ sin  ([B,B]@[B,D]) ----------------
__global__ void sprop_kernel(const float* __restrict__ DA, const float* __restrict__ sin_,
                             float* __restrict__ sout)
{
    int i = blockIdx.x, d = threadIdx.x;
    if (d >= DIM) return;
    float acc = 0.f;
    for (int k = 0; k < NBATCH; ++k) acc += DA[i * NBATCH + k] * sin_[k * DIM + d];
    sout[i * DIM + d] = acc;
}

__global__ void sess_final_kernel(const float* __restrict__ s, const float* __restrict__ s1,
                                  const float* __restrict__ s2, float* __restrict__ out2)
{
    int i = blockIdx.x, d = threadIdx.x;
    if (d >= DIM) return;
    int o = i * DIM + d;
    out2[o] = (s[o] + s1[o] + s2[o]) * (1.f / 3.f);
}

// ---------------- intra attention + final combine ----------------
// blockIdx.x = b*2 + half; rows i in [half*RPB, half*RPB+RPB)
__global__ __launch_bounds__(256) void intra_kernel(
    const int* __restrict__ inputs, const int* __restrict__ edge,
    const int* __restrict__ sess_item,
    const float* __restrict__ emb, const float* __restrict__ y1,
    const float* __restrict__ y2,
    const float* __restrict__ a0, const float* __restrict__ a1,
    const float* __restrict__ a2, const float* __restrict__ a3,
    float* __restrict__ out)
{
    __shared__ float h[NSEQ][DIM + 1];   // stride 101 (odd) -> bank-friendly
    __shared__ float al[RPB][NSEQ];
    __shared__ float av[4][DIM];
    int b = blockIdx.x >> 1;
    int half = blockIdx.x & 1;
    int tid = threadIdx.x;

    for (int idx = tid; idx < NSEQ * DIM; idx += 256) {
        int n = idx / DIM, d = idx - n * DIM;
        h[n][d] = emb[(size_t)inputs[b * NSEQ + n] * DIM + d];
    }
    for (int idx = tid; idx < 4 * DIM; idx += 256) {
        int k = idx / DIM, d = idx - k * DIM;
        const float* ap = (k == 0) ? a0 : (k == 1) ? a1 : (k == 2) ? a2 : a3;
        av[k][d] = ap[d];
    }
    __syncthreads();

    // phase A: selected logits. adjacency value picks ONE of the 4 e_k.
    for (int p = tid; p < RPB * NSEQ; p += 256) {
        int il = p / NSEQ, j = p - il * NSEQ;
        int i = half * RPB + il;
        int em = edge[(size_t)b * NSEQ * NSEQ + i * NSEQ + j];
        float val = -9e15f;
        if (em >= 1 && em <= 4) {
            const float* a = av[em - 1];
            float sdot = 0.f;
            #pragma unroll 4
            for (int d = 0; d < DIM; ++d) sdot += h[i][d] * h[j][d] * a[d];
            val = sdot >= 0.f ? sdot : LEAKY_ALPHA * sdot;
        }
        al[il][j] = val;
    }
    __syncthreads();

    // phase B: row softmax (serial per row; 35 rows, tiny)
    if (tid < RPB) {
        float m = -INFINITY;
        for (int j = 0; j < NSEQ; ++j) m = fmaxf(m, al[tid][j]);
        float ssum = 0.f;
        for (int j = 0; j < NSEQ; ++j) {
            float ex = __expf(al[tid][j] - m);
            al[tid][j] = ex;
            ssum += ex;
        }
        float inv = 1.f / ssum;
        for (int j = 0; j < NSEQ; ++j) al[tid][j] *= inv;
    }
    __syncthreads();

    // phase C: out[b,i,d] = sum_j alpha[i,j]*h[j,d] + inter_pad[sess_item[b,i], d]
    for (int p = tid; p < RPB * DIM; p += 256) {
        int il = p / DIM, d = p - il * DIM;
        int i = half * RPB + il;
        float acc = 0.f;
        #pragma unroll 5
        for (int j = 0; j < NSEQ; ++j) acc += al[il][j] * h[j][d];
        int r = sess_item[b * NSEQ + i];
        if (r > 0) {
            size_t o = (size_t)(r - 1) * DIM + d;
            acc += (emb[o] + y1[o] + y2[o]) * (1.f / 3.f);
        }
        out[(size_t)b * NSEQ * DIM + (size_t)i * DIM + d] = acc;
    }
}

extern "C" void kernel_launch(void* const* d_in, const int* in_sizes, int n_in,
                              void* d_out, int out_size, void* d_ws, size_t ws_size,
                              hipStream_t stream) {
    const int*   inputs    = (const int*)d_in[0];
    const int*   edge      = (const int*)d_in[1];
    // d_in[2] mask: unused; d_in[3] reversed_sess_item: unused
    const int*   sess_item = (const int*)d_in[4];
    const float* Dm        = (const float*)d_in[5];
    const float* Am        = (const float*)d_in[6];
    const float* sess_len  = (const float*)d_in[7];
    const float* emb       = (const float*)d_in[8];
    const float* a0        = (const float*)d_in[9];
    const float* a1        = (const float*)d_in[10];
    const float* a2        = (const float*)d_in[11];
    const float* a3        = (const float*)d_in[12];
    const int*   arows     = (const int*)d_in[13];
    const int*   acols     = (const int*)d_in[14];
    const float* avals     = (const float*)d_in[15];

    float* out      = (float*)d_out;                     // [B,N,D] = 896000
    float* out_sess = out + (size_t)NBATCH * NSEQ * DIM; // [B,D]   = 12800

    const size_t MAT = (size_t)NUM_NODE * DIM * sizeof(float);   // 16,000,000 B
    char* ws = (char*)d_ws;
    float* y1 = (float*)ws;
    float* y2 = (float*)(ws + MAT);
    char*  base2 = ws + 2 * MAT;
    float* s        = (float*)(base2 + 0);
    float* DA       = (float*)(base2 + 65536);
    float* s1       = (float*)(base2 + 2 * 65536);
    float* s2       = (float*)(base2 + 3 * 65536);
    int*   cnt      = (int*)(base2 + 4 * 65536);             // 160,000 B
    int*   rowst    = (int*)(base2 + 4 * 65536 + 163840);    // 160,000 B
    int2*  edata    = (int2*)(base2 + 4 * 65536 + 2 * 163840); // 5,120,000 B

    // ---- CSR build (per launch; deterministic recompute) ----
    hipMemsetAsync(cnt, 0, NUM_NODE * sizeof(int), stream);
    hist_kernel<<<(NEDGE + 255) / 256, 256, 0, stream>>>(arows, cnt);
    scan_kernel<<<1, 1024, 0, stream>>>(cnt, rowst);
    scatter_kernel<<<(NEDGE + 255) / 256, 256, 0, stream>>>(arows, acols, avals,
                                                            rowst, edata);

    // ---- inter: two propagation layers, gather-based (no atomics) ----
    const int prop_blocks = (NUM_NODE * 25 + 255) / 256;   // 3907
    csr_spmm_kernel<<<prop_blocks, 256, 0, stream>>>(rowst, edata, emb, y1);
    csr_spmm_kernel<<<prop_blocks, 256, 0, stream>>>(rowst, edata, y1, y2);

    // ---- session chain ----
    sess_sum_kernel<<<NBATCH, 128, 0, stream>>>(sess_item, emb, sess_len, s);
    da_kernel<<<NBATCH, NBATCH, 0, stream>>>(Dm, Am, DA);
    sprop_kernel<<<NBATCH, 128, 0, stream>>>(DA, s, s1);
    sprop_kernel<<<NBATCH, 128, 0, stream>>>(DA, s1, s2);
    sess_final_kernel<<<NBATCH, 128, 0, stream>>>(s, s1, s2, out_sess);

    // ---- intra attention + fused inter-gather + final add ----
    intra_kernel<<<NBATCH * 2, 256, 0, stream>>>(inputs, edge, sess_item,
                                                 emb, y1, y2, a0, a1, a2, a3, out);
}

// Round 3
// 265.763 us; speedup vs baseline: 7.6704x; 1.2244x over previous
//
#include <hip/hip_runtime.h>
#include <hip/hip_bf16.h>

#define NUM_NODE 40000
#define DIM 100
#define NBATCH 128
#define NSEQ 70
#define NEDGE 640000
#define LEAKY_ALPHA 0.2f
#define RPB 35   // intra rows per block (2 blocks per batch)

// ---------------- CSR build: histogram ----------------
__global__ __launch_bounds__(256) void hist_kernel(const int* __restrict__ rows,
                                                   int* __restrict__ cnt)
{
    int gid = blockIdx.x * 256 + threadIdx.x;
    if (gid < NEDGE) atomicAdd(&cnt[rows[gid]], 1);
}

// ---------------- hierarchical exclusive scan, pass 1 ----------------
// 40 blocks x 1024 threads; block-local exclusive scan + block sums.
__global__ __launch_bounds__(1024) void scan1_kernel(const int* __restrict__ cnt,
                                                     int* __restrict__ row_start,
                                                     int* __restrict__ bsum)
{
    __shared__ int wsum[16];
    int tid = threadIdx.x;
    int i = blockIdx.x * 1024 + tid;
    int v = (i < NUM_NODE) ? cnt[i] : 0;
    int lane = tid & 63, wid = tid >> 6;
    int x = v;
    #pragma unroll
    for (int off = 1; off < 64; off <<= 1) {
        int t = __shfl_up(x, off, 64);
        if (lane >= off) x += t;
    }
    if (lane == 63) wsum[wid] = x;
    __syncthreads();
    if (wid == 0) {
        int w = (lane < 16) ? wsum[lane] : 0;
        #pragma unroll
        for (int off = 1; off < 16; off <<= 1) {
            int t = __shfl_up(w, off, 64);
            if (lane >= off) w += t;
        }
        if (lane < 16) wsum[lane] = w;
    }
    __syncthreads();
    int base = (wid > 0) ? wsum[wid - 1] : 0;
    int incl = base + x;
    if (i < NUM_NODE) row_start[i] = incl - v;   // exclusive
    if (tid == 1023) bsum[blockIdx.x] = incl;    // block total
}

// ---------------- pass 2: exclusive scan of 40 block sums (one wave) -----------
__global__ void scan2_kernel(int* __restrict__ bsum, int nblocks)
{
    int lane = threadIdx.x;
    int v = (lane < nblocks) ? bsum[lane] : 0;
    int x = v;
    #pragma unroll
    for (int off = 1; off < 64; off <<= 1) {
        int t = __shfl_up(x, off, 64);
        if (lane >= off) x += t;
    }
    if (lane < nblocks) bsum[lane] = x - v;      // exclusive
}

// ---------------- pass 3: add block offsets ----------------
__global__ __launch_bounds__(1024) void scan3_kernel(int* __restrict__ row_start,
                                                     const int* __restrict__ bsum)
{
    int i = blockIdx.x * 1024 + threadIdx.x;
    if (i < NUM_NODE) row_start[i] += bsum[blockIdx.x];
}

// ---------------- CSR build: scatter (mutates row_start -> becomes row END) ----
__global__ __launch_bounds__(256) void scatter_kernel(
    const int* __restrict__ rows, const int* __restrict__ cols,
    const float* __restrict__ vals, int* __restrict__ row_start,
    int2* __restrict__ edge_data)
{
    int gid = blockIdx.x * 256 + threadIdx.x;
    if (gid >= NEDGE) return;
    int r = rows[gid];
    int pos = atomicAdd(&row_start[r], 1);
    edge_data[pos] = make_int2(cols[gid], __float_as_int(vals[gid]));
}

// ---------------- CSR SpMM: y[r] = sum_e val[e] * x[col[e]]  (no atomics) ------
// After scatter: row r spans [ (r?row_start[r-1]:0), row_start[r] ).
// 25 threads per row, one float4 chunk each.
__global__ __launch_bounds__(256) void csr_spmm_kernel(
    const int* __restrict__ row_start, const int2* __restrict__ edge_data,
    const float* __restrict__ x, float* __restrict__ y)
{
    int gid = blockIdx.x * 256 + threadIdx.x;   // NUM_NODE*25 = 1,000,000
    int r = gid / 25;
    int c = gid - r * 25;
    if (r >= NUM_NODE) return;
    int s0 = (r > 0) ? row_start[r - 1] : 0;
    int s1 = row_start[r];
    float4 acc = make_float4(0.f, 0.f, 0.f, 0.f);
    for (int e = s0; e < s1; ++e) {
        int2 ed = edge_data[e];
        float v = __int_as_float(ed.y);
        const float4 xv = *reinterpret_cast<const float4*>(x + (size_t)ed.x * DIM + c * 4);
        acc.x += v * xv.x;
        acc.y += v * xv.y;
        acc.z += v * xv.z;
        acc.w += v * xv.w;
    }
    *reinterpret_cast<float4*>(y + (size_t)r * DIM + c * 4) = acc;
}

// ---------------- session: s[b,d] = (1/len) * sum_n emb_pad[sess_item[b,n], d] ----
__global__ void sess_sum_kernel(const int* __restrict__ sess_item,
                                const float* __restrict__ emb,
                                const float* __restrict__ sess_len,
                                float* __restrict__ s)
{
    int b = blockIdx.x, d = threadIdx.x;
    if (d >= DIM) return;
    float acc = 0.f;
    for (int n = 0; n < NSEQ; ++n) {
        int r = sess_item[b * NSEQ + n];
        if (r > 0) acc += emb[(size_t)(r - 1) * DIM + d];
    }
    s[b * DIM + d] = acc / sess_len[b];
}

// ---------------- DA = D @ A  (128x128) ----------------
__global__ void da_kernel(const float* __restrict__ Dm, const float* __restrict__ Am,
                          float* __restrict__ DA)
{
    int i = blockIdx.x, j = threadIdx.x;
    float acc = 0.f;
    for (int k = 0; k < NBATCH; ++k) acc += Dm[i * NBATCH + k] * Am[k * NBATCH + j];
    DA[i * NBATCH + j] = acc;
}

// ---------------- sout = DA @ sin  ([B,B]@[B,D]) ----------------
__global__ void sprop_kernel(const float* __restrict__ DA, const float* __restrict__ sin_,
                             float* __restrict__ sout)
{
    int i = blockIdx.x, d = threadIdx.x;
    if (d >= DIM) return;
    float acc = 0.f;
    for (int k = 0; k < NBATCH; ++k) acc += DA[i * NBATCH + k] * sin_[k * DIM + d];
    sout[i * DIM + d] = acc;
}

__global__ void sess_final_kernel(const float* __restrict__ s, const float* __restrict__ s1,
                                  const float* __restrict__ s2, float* __restrict__ out2)
{
    int i = blockIdx.x, d = threadIdx.x;
    if (d >= DIM) return;
    int o = i * DIM + d;
    out2[o] = (s[o] + s1[o] + s2[o]) * (1.f / 3.f);
}

// ---------------- intra attention + final combine ----------------
// blockIdx.x = b*2 + half; rows i in [half*RPB, half*RPB+RPB)
__global__ __launch_bounds__(256) void intra_kernel(
    const int* __restrict__ inputs, const int* __restrict__ edge,
    const int* __restrict__ sess_item,
    const float* __restrict__ emb, const float* __restrict__ y1,
    const float* __restrict__ y2,
    const float* __restrict__ a0, const float* __restrict__ a1,
    const float* __restrict__ a2, const float* __restrict__ a3,
    float* __restrict__ out)
{
    __shared__ float h[NSEQ][DIM + 1];   // stride 101 (odd) -> bank-friendly
    __shared__ float al[RPB][NSEQ];
    __shared__ float av[4][DIM];
    int b = blockIdx.x >> 1;
    int half = blockIdx.x & 1;
    int tid = threadIdx.x;

    for (int idx = tid; idx < NSEQ * DIM; idx += 256) {
        int n = idx / DIM, d = idx - n * DIM;
        h[n][d] = emb[(size_t)inputs[b * NSEQ + n] * DIM + d];
    }
    for (int idx = tid; idx < 4 * DIM; idx += 256) {
        int k = idx / DIM, d = idx - k * DIM;
        const float* ap = (k == 0) ? a0 : (k == 1) ? a1 : (k == 2) ? a2 : a3;
        av[k][d] = ap[d];
    }
    __syncthreads();

    // phase A: selected logits. adjacency value picks ONE of the 4 e_k.
    for (int p = tid; p < RPB * NSEQ; p += 256) {
        int il = p / NSEQ, j = p - il * NSEQ;
        int i = half * RPB + il;
        int em = edge[(size_t)b * NSEQ * NSEQ + i * NSEQ + j];
        float val = -9e15f;
        if (em >= 1 && em <= 4) {
            const float* a = av[em - 1];
            float sdot = 0.f;
            #pragma unroll 4
            for (int d = 0; d < DIM; ++d) sdot += h[i][d] * h[j][d] * a[d];
            val = sdot >= 0.f ? sdot : LEAKY_ALPHA * sdot;
        }
        al[il][j] = val;
    }
    __syncthreads();

    // phase B: row softmax (serial per row; 35 rows, tiny)
    if (tid < RPB) {
        float m = -INFINITY;
        for (int j = 0; j < NSEQ; ++j) m = fmaxf(m, al[tid][j]);
        float ssum = 0.f;
        for (int j = 0; j < NSEQ; ++j) {
            float ex = __expf(al[tid][j] - m);
            al[tid][j] = ex;
            ssum += ex;
        }
        float inv = 1.f / ssum;
        for (int j = 0; j < NSEQ; ++j) al[tid][j] *= inv;
    }
    __syncthreads();

    // phase C: out[b,i,d] = sum_j alpha[i,j]*h[j,d] + inter_pad[sess_item[b,i], d]
    for (int p = tid; p < RPB * DIM; p += 256) {
        int il = p / DIM, d = p - il * DIM;
        int i = half * RPB + il;
        float acc = 0.f;
        #pragma unroll 5
        for (int j = 0; j < NSEQ; ++j) acc += al[il][j] * h[j][d];
        int r = sess_item[b * NSEQ + i];
        if (r > 0) {
            size_t o = (size_t)(r - 1) * DIM + d;
            acc += (emb[o] + y1[o] + y2[o]) * (1.f / 3.f);
        }
        out[(size_t)b * NSEQ * DIM + (size_t)i * DIM + d] = acc;
    }
}

extern "C" void kernel_launch(void* const* d_in, const int* in_sizes, int n_in,
                              void* d_out, int out_size, void* d_ws, size_t ws_size,
                              hipStream_t stream) {
    const int*   inputs    = (const int*)d_in[0];
    const int*   edge      = (const int*)d_in[1];
    // d_in[2] mask: unused; d_in[3] reversed_sess_item: unused
    const int*   sess_item = (const int*)d_in[4];
    const float* Dm        = (const float*)d_in[5];
    const float* Am        = (const float*)d_in[6];
    const float* sess_len  = (const float*)d_in[7];
    const float* emb       = (const float*)d_in[8];
    const float* a0        = (const float*)d_in[9];
    const float* a1        = (const float*)d_in[10];
    const float* a2        = (const float*)d_in[11];
    const float* a3        = (const float*)d_in[12];
    const int*   arows     = (const int*)d_in[13];
    const int*   acols     = (const int*)d_in[14];
    const float* avals     = (const float*)d_in[15];

    float* out      = (float*)d_out;                     // [B,N,D] = 896000
    float* out_sess = out + (size_t)NBATCH * NSEQ * DIM; // [B,D]   = 12800

    const size_t MAT = (size_t)NUM_NODE * DIM * sizeof(float);   // 16,000,000 B
    char* ws = (char*)d_ws;
    float* y1 = (float*)ws;
    float* y2 = (float*)(ws + MAT);
    char*  base2 = ws + 2 * MAT;
    float* s        = (float*)(base2 + 0);
    float* DA       = (float*)(base2 + 65536);
    float* s1       = (float*)(base2 + 2 * 65536);
    float* s2       = (float*)(base2 + 3 * 65536);
    int*   cnt      = (int*)(base2 + 4 * 65536);             // 160,000 B
    int*   rowst    = (int*)(base2 + 4 * 65536 + 163840);    // 160,000 B
    int*   bsum     = (int*)(base2 + 4 * 65536 + 2 * 163840); // 256 B
    int2*  edata    = (int2*)(base2 + 4 * 65536 + 2 * 163840 + 4096);

    const int SCAN_BLOCKS = (NUM_NODE + 1023) / 1024;  // 40

    // ---- CSR build (per launch; deterministic recompute) ----
    hipMemsetAsync(cnt, 0, NUM_NODE * sizeof(int), stream);
    hist_kernel<<<(NEDGE + 255) / 256, 256, 0, stream>>>(arows, cnt);
    scan1_kernel<<<SCAN_BLOCKS, 1024, 0, stream>>>(cnt, rowst, bsum);
    scan2_kernel<<<1, 64, 0, stream>>>(bsum, SCAN_BLOCKS);
    scan3_kernel<<<SCAN_BLOCKS, 1024, 0, stream>>>(rowst, bsum);
    scatter_kernel<<<(NEDGE + 255) / 256, 256, 0, stream>>>(arows, acols, avals,
                                                            rowst, edata);

    // ---- inter: two propagation layers, gather-based (no atomics) ----
    const int prop_blocks = (NUM_NODE * 25 + 255) / 256;   // 3907
    csr_spmm_kernel<<<prop_blocks, 256, 0, stream>>>(rowst, edata, emb, y1);
    csr_spmm_kernel<<<prop_blocks, 256, 0, stream>>>(rowst, edata, y1, y2);

    // ---- session chain ----
    sess_sum_kernel<<<NBATCH, 128, 0, stream>>>(sess_item, emb, sess_len, s);
    da_kernel<<<NBATCH, NBATCH, 0, stream>>>(Dm, Am, DA);
    sprop_kernel<<<NBATCH, 128, 0, stream>>>(DA, s, s1);
    sprop_kernel<<<NBATCH, 128, 0, stream>>>(DA, s1, s2);
    sess_final_kernel<<<NBATCH, 128, 0, stream>>>(s, s1, s2, out_sess);

    // ---- intra attention + fused inter-gather + final add ----
    intra_kernel<<<NBATCH * 2, 256, 0, stream>>>(inputs, edge, sess_item,
                                                 emb, y1, y2, a0, a1, a2, a3, out);
}

// Round 4
// 211.668 us; speedup vs baseline: 9.6307x; 1.2556x over previous
//
#include <hip/hip_runtime.h>
#include <hip/hip_bf16.h>

#define NUM_NODE 40000
#define DIM 100
#define NBATCH 128
#define NSEQ 70
#define NEDGE 640000
#define LEAKY_ALPHA 0.2f
#define RPB 35    // intra rows per block (2 blocks per batch)
#define HPAD 116  // LDS row stride (floats): 16B-aligned, bank-stride 20 -> good spread

__device__ __forceinline__ float bf2f(unsigned short u) {
    return __uint_as_float(((unsigned int)u) << 16);
}
__device__ __forceinline__ unsigned short f2bf(float f) {
    unsigned int u = __float_as_uint(f);
    return (unsigned short)((u + 0x7FFFu + ((u >> 16) & 1u)) >> 16);  // RNE
}

// ---------------- fp32 -> bf16 bulk convert (float4 in, ushort4 out) ----------
__global__ __launch_bounds__(256) void f2bf_kernel(const float* __restrict__ in,
                                                   unsigned short* __restrict__ out,
                                                   int n4)
{
    int i = blockIdx.x * 256 + threadIdx.x;
    if (i < n4) {
        float4 v = reinterpret_cast<const float4*>(in)[i];
        ushort4 o;
        o.x = f2bf(v.x); o.y = f2bf(v.y); o.z = f2bf(v.z); o.w = f2bf(v.w);
        reinterpret_cast<ushort4*>(out)[i] = o;
    }
}

// ---------------- CSR build: histogram ----------------
__global__ __launch_bounds__(256) void hist_kernel(const int* __restrict__ rows,
                                                   int* __restrict__ cnt)
{
    int gid = blockIdx.x * 256 + threadIdx.x;
    if (gid < NEDGE) atomicAdd(&cnt[rows[gid]], 1);
}

// ---------------- hierarchical exclusive scan, pass 1 ----------------
__global__ __launch_bounds__(1024) void scan1_kernel(const int* __restrict__ cnt,
                                                     int* __restrict__ row_start,
                                                     int* __restrict__ bsum)
{
    __shared__ int wsum[16];
    int tid = threadIdx.x;
    int i = blockIdx.x * 1024 + tid;
    int v = (i < NUM_NODE) ? cnt[i] : 0;
    int lane = tid & 63, wid = tid >> 6;
    int x = v;
    #pragma unroll
    for (int off = 1; off < 64; off <<= 1) {
        int t = __shfl_up(x, off, 64);
        if (lane >= off) x += t;
    }
    if (lane == 63) wsum[wid] = x;
    __syncthreads();
    if (wid == 0) {
        int w = (lane < 16) ? wsum[lane] : 0;
        #pragma unroll
        for (int off = 1; off < 16; off <<= 1) {
            int t = __shfl_up(w, off, 64);
            if (lane >= off) w += t;
        }
        if (lane < 16) wsum[lane] = w;
    }
    __syncthreads();
    int base = (wid > 0) ? wsum[wid - 1] : 0;
    int incl = base + x;
    if (i < NUM_NODE) row_start[i] = incl - v;   // exclusive
    if (tid == 1023) bsum[blockIdx.x] = incl;    // block total
}

// ---------------- pass 2: exclusive scan of 40 block sums (one wave) -----------
__global__ void scan2_kernel(int* __restrict__ bsum, int nblocks)
{
    int lane = threadIdx.x;
    int v = (lane < nblocks) ? bsum[lane] : 0;
    int x = v;
    #pragma unroll
    for (int off = 1; off < 64; off <<= 1) {
        int t = __shfl_up(x, off, 64);
        if (lane >= off) x += t;
    }
    if (lane < nblocks) bsum[lane] = x - v;      // exclusive
}

// ---------------- pass 3: add block offsets ----------------
__global__ __launch_bounds__(1024) void scan3_kernel(int* __restrict__ row_start,
                                                     const int* __restrict__ bsum)
{
    int i = blockIdx.x * 1024 + threadIdx.x;
    if (i < NUM_NODE) row_start[i] += bsum[blockIdx.x];
}

// ---------------- CSR build: scatter (mutates row_start -> becomes row END) ----
__global__ __launch_bounds__(256) void scatter_kernel(
    const int* __restrict__ rows, const int* __restrict__ cols,
    const float* __restrict__ vals, int* __restrict__ row_start,
    int2* __restrict__ edge_data)
{
    int gid = blockIdx.x * 256 + threadIdx.x;
    if (gid >= NEDGE) return;
    int r = rows[gid];
    int pos = atomicAdd(&row_start[r], 1);
    edge_data[pos] = make_int2(cols[gid], __float_as_int(vals[gid]));
}

// ---------------- CSR SpMM bf16: y[r] = sum_e val[e] * x[col[e]] ---------------
// Row r spans [ (r?row_start[r-1]:0), row_start[r] ). 25 lanes/row, 4 elems each.
// x,y are bf16 (halved gather traffic); accumulation in fp32.
__global__ __launch_bounds__(256) void csr_spmm_bf16_kernel(
    const int* __restrict__ row_start, const int2* __restrict__ edge_data,
    const unsigned short* __restrict__ x, unsigned short* __restrict__ y)
{
    int gid = blockIdx.x * 256 + threadIdx.x;   // NUM_NODE*25 = 1,000,000
    int r = gid / 25;
    int c = gid - r * 25;
    if (r >= NUM_NODE) return;
    int s0 = (r > 0) ? row_start[r - 1] : 0;
    int s1 = row_start[r];
    float a0 = 0.f, a1 = 0.f, a2 = 0.f, a3 = 0.f;
    for (int e = s0; e < s1; ++e) {
        int2 ed = edge_data[e];
        float v = __int_as_float(ed.y);
        ushort4 xv = *reinterpret_cast<const ushort4*>(x + (size_t)ed.x * DIM + c * 4);
        a0 += v * bf2f(xv.x);
        a1 += v * bf2f(xv.y);
        a2 += v * bf2f(xv.z);
        a3 += v * bf2f(xv.w);
    }
    ushort4 o;
    o.x = f2bf(a0); o.y = f2bf(a1); o.z = f2bf(a2); o.w = f2bf(a3);
    *reinterpret_cast<ushort4*>(y + (size_t)r * DIM + c * 4) = o;
}

// ---------------- session: s[b,d] = (1/len) * sum_n emb_pad[sess_item[b,n], d] ----
__global__ void sess_sum_kernel(const int* __restrict__ sess_item,
                                const float* __restrict__ emb,
                                const float* __restrict__ sess_len,
                                float* __restrict__ s)
{
    int b = blockIdx.x, d = threadIdx.x;
    if (d >= DIM) return;
    float acc = 0.f;
    for (int n = 0; n < NSEQ; ++n) {
        int r = sess_item[b * NSEQ + n];
        if (r > 0) acc += emb[(size_t)(r - 1) * DIM + d];
    }
    s[b * DIM + d] = acc / sess_len[b];
}

// ---------------- DA = D @ A  (128x128) ----------------
__global__ void da_kernel(const float* __restrict__ Dm, const float* __restrict__ Am,
                          float* __restrict__ DA)
{
    int i = blockIdx.x, j = threadIdx.x;
    float acc = 0.f;
    for (int k = 0; k < NBATCH; ++k) acc += Dm[i * NBATCH + k] * Am[k * NBATCH + j];
    DA[i * NBATCH + j] = acc;
}

// ---------------- sout = DA @ sin  ([B,B]@[B,D]) ----------------
__global__ void sprop_kernel(const float* __restrict__ DA, const float* __restrict__ sin_,
                             float* __restrict__ sout)
{
    int i = blockIdx.x, d = threadIdx.x;
    if (d >= DIM) return;
    float acc = 0.f;
    for (int k = 0; k < NBATCH; ++k) acc += DA[i * NBATCH + k] * sin_[k * DIM + d];
    sout[i * DIM + d] = acc;
}

__global__ void sess_final_kernel(const float* __restrict__ s, const float* __restrict__ s1,
                                  const float* __restrict__ s2, float* __restrict__ out2)
{
    int i = blockIdx.x, d = threadIdx.x;
    if (d >= DIM) return;
    int o = i * DIM + d;
    out2[o] = (s[o] + s1[o] + s2[o]) * (1.f / 3.f);
}

// ---------------- intra attention + final combine (v2: vectorized LDS) ---------
// blockIdx.x = b*2 + half; rows i in [half*RPB, half*RPB+RPB); 1024 threads.
__global__ __launch_bounds__(1024) void intra_kernel(
    const int* __restrict__ inputs, const int* __restrict__ edge,
    const int* __restrict__ sess_item,
    const float* __restrict__ emb, const unsigned short* __restrict__ y1,
    const unsigned short* __restrict__ y2,
    const float* __restrict__ a0, const float* __restrict__ a1,
    const float* __restrict__ a2, const float* __restrict__ a3,
    float* __restrict__ out)
{
    __shared__ float h[NSEQ][HPAD];
    __shared__ float av[4][HPAD];
    __shared__ float al[RPB][NSEQ + 2];
    int b = blockIdx.x >> 1;
    int half = blockIdx.x & 1;
    int tid = threadIdx.x;

    for (int idx = tid; idx < NSEQ * DIM; idx += 1024) {
        int n = idx / DIM, d = idx - n * DIM;
        h[n][d] = emb[(size_t)inputs[b * NSEQ + n] * DIM + d];
    }
    if (tid < 4 * DIM) {
        int k = tid / DIM, d = tid - k * DIM;
        const float* ap = (k == 0) ? a0 : (k == 1) ? a1 : (k == 2) ? a2 : a3;
        av[k][d] = ap[d];
    }
    __syncthreads();

    // phase A: selected logits via float4 LDS reads (ds_read_b128)
    for (int p = tid; p < RPB * NSEQ; p += 1024) {
        int il = p / NSEQ, j = p - il * NSEQ;
        int i = half * RPB + il;
        int em = edge[(size_t)b * NSEQ * NSEQ + i * NSEQ + j];
        float val = -9e15f;
        if (em >= 1 && em <= 4) {
            const float* hi = h[i];
            const float* hj = h[j];
            const float* a  = av[em - 1];
            float sx = 0.f, sy = 0.f, sz = 0.f, sw = 0.f;
            #pragma unroll
            for (int d = 0; d < DIM; d += 4) {
                float4 x1 = *reinterpret_cast<const float4*>(hi + d);
                float4 x2 = *reinterpret_cast<const float4*>(hj + d);
                float4 x3 = *reinterpret_cast<const float4*>(a + d);
                sx += x1.x * x2.x * x3.x;
                sy += x1.y * x2.y * x3.y;
                sz += x1.z * x2.z * x3.z;
                sw += x1.w * x2.w * x3.w;
            }
            float sd = (sx + sy) + (sz + sw);
            val = sd >= 0.f ? sd : LEAKY_ALPHA * sd;
        }
        al[il][j] = val;
    }
    __syncthreads();

    // phase B: wave-parallel row softmax (16 waves over 35 rows)
    int wid = tid >> 6, lane = tid & 63;
    for (int row = wid; row < RPB; row += 16) {
        float v0 = (lane < NSEQ) ? al[row][lane] : -INFINITY;
        float v1 = (lane + 64 < NSEQ) ? al[row][lane + 64] : -INFINITY;
        float m = fmaxf(v0, v1);
        #pragma unroll
        for (int off = 32; off >= 1; off >>= 1) m = fmaxf(m, __shfl_xor(m, off, 64));
        float e0 = (lane < NSEQ) ? __expf(v0 - m) : 0.f;
        float e1 = (lane + 64 < NSEQ) ? __expf(v1 - m) : 0.f;
        float ssum = e0 + e1;
        #pragma unroll
        for (int off = 32; off >= 1; off >>= 1) ssum += __shfl_xor(ssum, off, 64);
        float inv = 1.f / ssum;
        if (lane < NSEQ) al[row][lane] = e0 * inv;
        if (lane + 64 < NSEQ) al[row][lane + 64] = e1 * inv;
    }
    __syncthreads();

    // phase C: out[b,i,dc..dc+3] = sum_j alpha[i,j]*h[j,dc..] + inter_pad gather
    if (tid < RPB * 25) {
        int il = tid / 25, dc = (tid - il * 25) * 4;
        int i = half * RPB + il;
        float4 acc = make_float4(0.f, 0.f, 0.f, 0.f);
        for (int j = 0; j < NSEQ; ++j) {
            float w = al[il][j];
            float4 hv = *reinterpret_cast<const float4*>(&h[j][dc]);
            acc.x += w * hv.x;
            acc.y += w * hv.y;
            acc.z += w * hv.z;
            acc.w += w * hv.w;
        }
        int r = sess_item[b * NSEQ + i];
        if (r > 0) {
            size_t o = (size_t)(r - 1) * DIM + dc;
            float4 ev = *reinterpret_cast<const float4*>(emb + o);
            ushort4 u1 = *reinterpret_cast<const ushort4*>(y1 + o);
            ushort4 u2 = *reinterpret_cast<const ushort4*>(y2 + o);
            acc.x += (ev.x + bf2f(u1.x) + bf2f(u2.x)) * (1.f / 3.f);
            acc.y += (ev.y + bf2f(u1.y) + bf2f(u2.y)) * (1.f / 3.f);
            acc.z += (ev.z + bf2f(u1.z) + bf2f(u2.z)) * (1.f / 3.f);
            acc.w += (ev.w + bf2f(u1.w) + bf2f(u2.w)) * (1.f / 3.f);
        }
        *reinterpret_cast<float4*>(out + (size_t)b * NSEQ * DIM + (size_t)i * DIM + dc) = acc;
    }
}

extern "C" void kernel_launch(void* const* d_in, const int* in_sizes, int n_in,
                              void* d_out, int out_size, void* d_ws, size_t ws_size,
                              hipStream_t stream) {
    const int*   inputs    = (const int*)d_in[0];
    const int*   edge      = (const int*)d_in[1];
    // d_in[2] mask: unused; d_in[3] reversed_sess_item: unused
    const int*   sess_item = (const int*)d_in[4];
    const float* Dm        = (const float*)d_in[5];
    const float* Am        = (const float*)d_in[6];
    const float* sess_len  = (const float*)d_in[7];
    const float* emb       = (const float*)d_in[8];
    const float* a0        = (const float*)d_in[9];
    const float* a1        = (const float*)d_in[10];
    const float* a2        = (const float*)d_in[11];
    const float* a3        = (const float*)d_in[12];
    const int*   arows     = (const int*)d_in[13];
    const int*   acols     = (const int*)d_in[14];
    const float* avals     = (const float*)d_in[15];

    float* out      = (float*)d_out;                     // [B,N,D] = 896000
    float* out_sess = out + (size_t)NBATCH * NSEQ * DIM; // [B,D]   = 12800

    const size_t MATB = (size_t)NUM_NODE * DIM * sizeof(unsigned short); // 8,000,000 B
    char* ws = (char*)d_ws;
    unsigned short* embh = (unsigned short*)ws;
    unsigned short* y1   = (unsigned short*)(ws + MATB);
    unsigned short* y2   = (unsigned short*)(ws + 2 * MATB);
    char*  base2 = ws + 3 * MATB;
    float* s        = (float*)(base2 + 0);
    float* DA       = (float*)(base2 + 65536);
    float* s1       = (float*)(base2 + 2 * 65536);
    float* s2       = (float*)(base2 + 3 * 65536);
    int*   cnt      = (int*)(base2 + 4 * 65536);              // 160,000 B
    int*   rowst    = (int*)(base2 + 4 * 65536 + 163840);     // 160,000 B
    int*   bsum     = (int*)(base2 + 4 * 65536 + 2 * 163840); // 256 B
    int2*  edata    = (int2*)(base2 + 4 * 65536 + 2 * 163840 + 4096);

    const int SCAN_BLOCKS = (NUM_NODE + 1023) / 1024;  // 40

    // ---- emb -> bf16 (for halved gather traffic) ----
    f2bf_kernel<<<(NUM_NODE * DIM / 4 + 255) / 256, 256, 0, stream>>>(
        emb, embh, NUM_NODE * DIM / 4);

    // ---- CSR build (per launch; deterministic recompute) ----
    hipMemsetAsync(cnt, 0, NUM_NODE * sizeof(int), stream);
    hist_kernel<<<(NEDGE + 255) / 256, 256, 0, stream>>>(arows, cnt);
    scan1_kernel<<<SCAN_BLOCKS, 1024, 0, stream>>>(cnt, rowst, bsum);
    scan2_kernel<<<1, 64, 0, stream>>>(bsum, SCAN_BLOCKS);
    scan3_kernel<<<SCAN_BLOCKS, 1024, 0, stream>>>(rowst, bsum);
    scatter_kernel<<<(NEDGE + 255) / 256, 256, 0, stream>>>(arows, acols, avals,
                                                            rowst, edata);

    // ---- inter: two propagation layers, bf16 gather (no atomics) ----
    const int prop_blocks = (NUM_NODE * 25 + 255) / 256;   // 3907
    csr_spmm_bf16_kernel<<<prop_blocks, 256, 0, stream>>>(rowst, edata, embh, y1);
    csr_spmm_bf16_kernel<<<prop_blocks, 256, 0, stream>>>(rowst, edata, y1, y2);

    // ---- session chain ----
    sess_sum_kernel<<<NBATCH, 128, 0, stream>>>(sess_item, emb, sess_len, s);
    da_kernel<<<NBATCH, NBATCH, 0, stream>>>(Dm, Am, DA);
    sprop_kernel<<<NBATCH, 128, 0, stream>>>(DA, s, s1);
    sprop_kernel<<<NBATCH, 128, 0, stream>>>(DA, s1, s2);
    sess_final_kernel<<<NBATCH, 128, 0, stream>>>(s, s1, s2, out_sess);

    // ---- intra attention + fused inter-gather + final add ----
    intra_kernel<<<NBATCH * 2, 1024, 0, stream>>>(inputs, edge, sess_item,
                                                  emb, y1, y2, a0, a1, a2, a3, out);
}

// Round 5
// 201.605 us; speedup vs baseline: 10.1114x; 1.0499x over previous
//
#include <hip/hip_runtime.h>
#include <hip/hip_bf16.h>

#define NUM_NODE 40000
#define DIM 100
#define NBATCH 128
#define NSEQ 70
#define NEDGE 640000
#define LEAKY_ALPHA 0.2f
#define RPB 18    // intra rows per block (4 blocks per batch -> 2 blocks/CU)
#define HPAD 116  // LDS row stride (floats), 16B-aligned

__device__ __forceinline__ float bf2f(unsigned short u) {
    return __uint_as_float(((unsigned int)u) << 16);
}
__device__ __forceinline__ unsigned short f2bf(float f) {
    unsigned int u = __float_as_uint(f);
    return (unsigned short)((u + 0x7FFFu + ((u >> 16) & 1u)) >> 16);  // RNE
}

// ---------------- fused: fp32->bf16 convert (1M float4) + edge histogram -------
__global__ __launch_bounds__(256) void f2bf_hist_kernel(
    const float* __restrict__ in, unsigned short* __restrict__ out,
    const int* __restrict__ rows, int* __restrict__ cnt)
{
    int gid = blockIdx.x * 256 + threadIdx.x;
    if (gid < NUM_NODE * DIM / 4) {
        float4 v = reinterpret_cast<const float4*>(in)[gid];
        ushort4 o;
        o.x = f2bf(v.x); o.y = f2bf(v.y); o.z = f2bf(v.z); o.w = f2bf(v.w);
        reinterpret_cast<ushort4*>(out)[gid] = o;
    }
    if (gid < NEDGE) atomicAdd(&cnt[rows[gid]], 1);
}

// ---------------- hierarchical exclusive scan, pass 1 (+ zero mark array) ------
__global__ __launch_bounds__(1024) void scan1_kernel(const int* __restrict__ cnt,
                                                     int* __restrict__ row_start,
                                                     int* __restrict__ bsum,
                                                     unsigned char* __restrict__ mark)
{
    __shared__ int wsum[16];
    int tid = threadIdx.x;
    int i = blockIdx.x * 1024 + tid;
    if (i < NUM_NODE) mark[i] = 0;
    int v = (i < NUM_NODE) ? cnt[i] : 0;
    int lane = tid & 63, wid = tid >> 6;
    int x = v;
    #pragma unroll
    for (int off = 1; off < 64; off <<= 1) {
        int t = __shfl_up(x, off, 64);
        if (lane >= off) x += t;
    }
    if (lane == 63) wsum[wid] = x;
    __syncthreads();
    if (wid == 0) {
        int w = (lane < 16) ? wsum[lane] : 0;
        #pragma unroll
        for (int off = 1; off < 16; off <<= 1) {
            int t = __shfl_up(w, off, 64);
            if (lane >= off) w += t;
        }
        if (lane < 16) wsum[lane] = w;
    }
    __syncthreads();
    int base = (wid > 0) ? wsum[wid - 1] : 0;
    int incl = base + x;
    if (i < NUM_NODE) row_start[i] = incl - v;   // exclusive
    if (tid == 1023) bsum[blockIdx.x] = incl;    // block total
}

// ---------------- pass 2: exclusive scan of 40 block sums (one wave) -----------
__global__ void scan2_kernel(int* __restrict__ bsum, int nblocks)
{
    int lane = threadIdx.x;
    int v = (lane < nblocks) ? bsum[lane] : 0;
    int x = v;
    #pragma unroll
    for (int off = 1; off < 64; off <<= 1) {
        int t = __shfl_up(x, off, 64);
        if (lane >= off) x += t;
    }
    if (lane < nblocks) bsum[lane] = x - v;      // exclusive
}

// ---------------- pass 3: add block offsets ----------------
__global__ __launch_bounds__(1024) void scan3_kernel(int* __restrict__ row_start,
                                                     const int* __restrict__ bsum)
{
    int i = blockIdx.x * 1024 + threadIdx.x;
    if (i < NUM_NODE) row_start[i] += bsum[blockIdx.x];
}

// ---------------- scatter (row_start -> row END) + mark needed output rows -----
__global__ __launch_bounds__(256) void scatter_mark_kernel(
    const int* __restrict__ rows, const int* __restrict__ cols,
    const float* __restrict__ vals, int* __restrict__ row_start,
    int2* __restrict__ edge_data,
    const int* __restrict__ sess_item, unsigned char* __restrict__ mark)
{
    int gid = blockIdx.x * 256 + threadIdx.x;
    if (gid < NBATCH * NSEQ) {
        int r = sess_item[gid];
        if (r > 0) mark[r - 1] = 1;      // benign same-value race
    }
    if (gid >= NEDGE) return;
    int r = rows[gid];
    int pos = atomicAdd(&row_start[r], 1);
    edge_data[pos] = make_int2(cols[gid], __float_as_int(vals[gid]));
}

// ---------------- CSR SpMM bf16 (layer 1, all rows) ----------------
// Row r spans [ (r?row_start[r-1]:0), row_start[r] ). 25 lanes/row, 4 elems each.
__global__ __launch_bounds__(256) void csr_spmm_bf16_kernel(
    const int* __restrict__ row_start, const int2* __restrict__ edge_data,
    const unsigned short* __restrict__ x, unsigned short* __restrict__ y)
{
    int gid = blockIdx.x * 256 + threadIdx.x;   // NUM_NODE*25 = 1,000,000
    int r = gid / 25;
    int c = gid - r * 25;
    if (r >= NUM_NODE) return;
    int s0 = (r > 0) ? row_start[r - 1] : 0;
    int s1 = row_start[r];
    float a0 = 0.f, a1 = 0.f, a2 = 0.f, a3 = 0.f;
    for (int e = s0; e < s1; ++e) {
        int2 ed = edge_data[e];
        float v = __int_as_float(ed.y);
        ushort4 xv = *reinterpret_cast<const ushort4*>(x + (size_t)ed.x * DIM + c * 4);
        a0 += v * bf2f(xv.x);
        a1 += v * bf2f(xv.y);
        a2 += v * bf2f(xv.z);
        a3 += v * bf2f(xv.w);
    }
    ushort4 o;
    o.x = f2bf(a0); o.y = f2bf(a1); o.z = f2bf(a2); o.w = f2bf(a3);
    *reinterpret_cast<ushort4*>(y + (size_t)r * DIM + c * 4) = o;
}

// ---------------- CSR SpMM bf16 (layer 2, only rows consumed downstream) -------
__global__ __launch_bounds__(256) void csr_spmm_bf16_masked_kernel(
    const int* __restrict__ row_start, const int2* __restrict__ edge_data,
    const unsigned short* __restrict__ x, unsigned short* __restrict__ y,
    const unsigned char* __restrict__ mark)
{
    int gid = blockIdx.x * 256 + threadIdx.x;
    int r = gid / 25;
    int c = gid - r * 25;
    if (r >= NUM_NODE || !mark[r]) return;
    int s0 = (r > 0) ? row_start[r - 1] : 0;
    int s1 = row_start[r];
    float a0 = 0.f, a1 = 0.f, a2 = 0.f, a3 = 0.f;
    for (int e = s0; e < s1; ++e) {
        int2 ed = edge_data[e];
        float v = __int_as_float(ed.y);
        ushort4 xv = *reinterpret_cast<const ushort4*>(x + (size_t)ed.x * DIM + c * 4);
        a0 += v * bf2f(xv.x);
        a1 += v * bf2f(xv.y);
        a2 += v * bf2f(xv.z);
        a3 += v * bf2f(xv.w);
    }
    ushort4 o;
    o.x = f2bf(a0); o.y = f2bf(a1); o.z = f2bf(a2); o.w = f2bf(a3);
    *reinterpret_cast<ushort4*>(y + (size_t)r * DIM + c * 4) = o;
}

// ---------------- fused session: s (gather-mean) ∥ DA = D@A --------------------
// blocks 0..127: s[b,:]; blocks 128..255: DA row (b-128)
__global__ __launch_bounds__(128) void sess_da_kernel(
    const int* __restrict__ sess_item, const float* __restrict__ emb,
    const float* __restrict__ sess_len,
    const float* __restrict__ Dm, const float* __restrict__ Am,
    float* __restrict__ s, float* __restrict__ DA)
{
    int blk = blockIdx.x, t = threadIdx.x;
    if (blk < NBATCH) {
        if (t >= DIM) return;
        float acc = 0.f;
        for (int n = 0; n < NSEQ; ++n) {
            int r = sess_item[blk * NSEQ + n];
            if (r > 0) acc += emb[(size_t)(r - 1) * DIM + t];
        }
        s[blk * DIM + t] = acc / sess_len[blk];
    } else {
        int i = blk - NBATCH;
        float acc = 0.f;
        for (int k = 0; k < NBATCH; ++k) acc += Dm[i * NBATCH + k] * Am[k * NBATCH + t];
        DA[i * NBATCH + t] = acc;
    }
}

// ---------------- s1 = DA @ s ----------------
__global__ __launch_bounds__(128) void sprop_kernel(const float* __restrict__ DA,
                                                    const float* __restrict__ sin_,
                                                    float* __restrict__ sout)
{
    int i = blockIdx.x, d = threadIdx.x;
    if (d >= DIM) return;
    float acc = 0.f;
    for (int k = 0; k < NBATCH; ++k) acc += DA[i * NBATCH + k] * sin_[k * DIM + d];
    sout[i * DIM + d] = acc;
}

// ---------------- s2 = DA @ s1; out2 = (s+s1+s2)/3 (fused) ----------------
__global__ __launch_bounds__(128) void sprop_final_kernel(
    const float* __restrict__ DA, const float* __restrict__ s,
    const float* __restrict__ s1, float* __restrict__ out2)
{
    int i = blockIdx.x, d = threadIdx.x;
    if (d >= DIM) return;
    float acc = 0.f;
    for (int k = 0; k < NBATCH; ++k) acc += DA[i * NBATCH + k] * s1[k * DIM + d];
    int o = i * DIM + d;
    out2[o] = (s[o] + s1[o] + acc) * (1.f / 3.f);
}

// ---------------- intra attention + final combine (v3: 2 blocks/CU) ------------
// blockIdx.x = b*4 + q; rows i in [q*RPB, min(q*RPB+RPB, 70))
__global__ __launch_bounds__(1024) void intra_kernel(
    const int* __restrict__ inputs, const int* __restrict__ edge,
    const int* __restrict__ sess_item,
    const float* __restrict__ emb, const unsigned short* __restrict__ y1,
    const unsigned short* __restrict__ y2,
    const float* __restrict__ a0, const float* __restrict__ a1,
    const float* __restrict__ a2, const float* __restrict__ a3,
    float* __restrict__ out)
{
    __shared__ float h[NSEQ][HPAD];
    __shared__ float av[4][HPAD];
    __shared__ float al[RPB][NSEQ + 2];
    int b = blockIdx.x >> 2;
    int q = blockIdx.x & 3;
    int i0 = q * RPB;
    int nrows = (i0 + RPB <= NSEQ) ? RPB : (NSEQ - i0);
    int tid = threadIdx.x;

    for (int idx = tid; idx < NSEQ * DIM; idx += 1024) {
        int n = idx / DIM, d = idx - n * DIM;
        h[n][d] = emb[(size_t)inputs[b * NSEQ + n] * DIM + d];
    }
    if (tid < 4 * DIM) {
        int k = tid / DIM, d = tid - k * DIM;
        const float* ap = (k == 0) ? a0 : (k == 1) ? a1 : (k == 2) ? a2 : a3;
        av[k][d] = ap[d];
    }
    __syncthreads();

    // phase A: selected logits via float4 LDS reads
    for (int p = tid; p < nrows * NSEQ; p += 1024) {
        int il = p / NSEQ, j = p - il * NSEQ;
        int i = i0 + il;
        int em = edge[(size_t)b * NSEQ * NSEQ + i * NSEQ + j];
        float val = -9e15f;
        if (em >= 1 && em <= 4) {
            const float* hi = h[i];
            const float* hj = h[j];
            const float* a  = av[em - 1];
            float sx = 0.f, sy = 0.f, sz = 0.f, sw = 0.f;
            #pragma unroll
            for (int d = 0; d < DIM; d += 4) {
                float4 x1 = *reinterpret_cast<const float4*>(hi + d);
                float4 x2 = *reinterpret_cast<const float4*>(hj + d);
                float4 x3 = *reinterpret_cast<const float4*>(a + d);
                sx += x1.x * x2.x * x3.x;
                sy += x1.y * x2.y * x3.y;
                sz += x1.z * x2.z * x3.z;
                sw += x1.w * x2.w * x3.w;
            }
            float sd = (sx + sy) + (sz + sw);
            val = sd >= 0.f ? sd : LEAKY_ALPHA * sd;
        }
        al[il][j] = val;
    }
    __syncthreads();

    // phase B: wave-parallel row softmax
    int wid = tid >> 6, lane = tid & 63;
    for (int row = wid; row < nrows; row += 16) {
        float v0 = (lane < NSEQ) ? al[row][lane] : -INFINITY;
        float v1 = (lane + 64 < NSEQ) ? al[row][lane + 64] : -INFINITY;
        float m = fmaxf(v0, v1);
        #pragma unroll
        for (int off = 32; off >= 1; off >>= 1) m = fmaxf(m, __shfl_xor(m, off, 64));
        float e0 = (lane < NSEQ) ? __expf(v0 - m) : 0.f;
        float e1 = (lane + 64 < NSEQ) ? __expf(v1 - m) : 0.f;
        float ssum = e0 + e1;
        #pragma unroll
        for (int off = 32; off >= 1; off >>= 1) ssum += __shfl_xor(ssum, off, 64);
        float inv = 1.f / ssum;
        if (lane < NSEQ) al[row][lane] = e0 * inv;
        if (lane + 64 < NSEQ) al[row][lane + 64] = e1 * inv;
    }
    __syncthreads();

    // phase C: out += alpha@h + inter_pad gather
    if (tid < nrows * 25) {
        int il = tid / 25, dc = (tid - il * 25) * 4;
        int i = i0 + il;
        float4 acc = make_float4(0.f, 0.f, 0.f, 0.f);
        for (int j = 0; j < NSEQ; ++j) {
            float w = al[il][j];
            float4 hv = *reinterpret_cast<const float4*>(&h[j][dc]);
            acc.x += w * hv.x;
            acc.y += w * hv.y;
            acc.z += w * hv.z;
            acc.w += w * hv.w;
        }
        int r = sess_item[b * NSEQ + i];
        if (r > 0) {
            size_t o = (size_t)(r - 1) * DIM + dc;
            float4 ev = *reinterpret_cast<const float4*>(emb + o);
            ushort4 u1 = *reinterpret_cast<const ushort4*>(y1 + o);
            ushort4 u2 = *reinterpret_cast<const ushort4*>(y2 + o);
            acc.x += (ev.x + bf2f(u1.x) + bf2f(u2.x)) * (1.f / 3.f);
            acc.y += (ev.y + bf2f(u1.y) + bf2f(u2.y)) * (1.f / 3.f);
            acc.z += (ev.z + bf2f(u1.z) + bf2f(u2.z)) * (1.f / 3.f);
            acc.w += (ev.w + bf2f(u1.w) + bf2f(u2.w)) * (1.f / 3.f);
        }
        *reinterpret_cast<float4*>(out + (size_t)b * NSEQ * DIM + (size_t)i * DIM + dc) = acc;
    }
}

extern "C" void kernel_launch(void* const* d_in, const int* in_sizes, int n_in,
                              void* d_out, int out_size, void* d_ws, size_t ws_size,
                              hipStream_t stream) {
    const int*   inputs    = (const int*)d_in[0];
    const int*   edge      = (const int*)d_in[1];
    // d_in[2] mask: unused; d_in[3] reversed_sess_item: unused
    const int*   sess_item = (const int*)d_in[4];
    const float* Dm        = (const float*)d_in[5];
    const float* Am        = (const float*)d_in[6];
    const float* sess_len  = (const float*)d_in[7];
    const float* emb       = (const float*)d_in[8];
    const float* a0        = (const float*)d_in[9];
    const float* a1        = (const float*)d_in[10];
    const float* a2        = (const float*)d_in[11];
    const float* a3        = (const float*)d_in[12];
    const int*   arows     = (const int*)d_in[13];
    const int*   acols     = (const int*)d_in[14];
    const float* avals     = (const float*)d_in[15];

    float* out      = (float*)d_out;                     // [B,N,D] = 896000
    float* out_sess = out + (size_t)NBATCH * NSEQ * DIM; // [B,D]   = 12800

    const size_t MATB = (size_t)NUM_NODE * DIM * sizeof(unsigned short); // 8,000,000 B
    char* ws = (char*)d_ws;
    unsigned short* embh = (unsigned short*)ws;
    unsigned short* y1   = (unsigned short*)(ws + MATB);
    unsigned short* y2   = (unsigned short*)(ws + 2 * MATB);
    char*  base2 = ws + 3 * MATB;
    float* s        = (float*)(base2 + 0);
    float* DA       = (float*)(base2 + 65536);
    float* s1       = (float*)(base2 + 2 * 65536);
    int*   cnt      = (int*)(base2 + 3 * 65536);              // 160,000 B
    int*   rowst    = (int*)(base2 + 3 * 65536 + 163840);     // 160,000 B
    int*   bsum     = (int*)(base2 + 3 * 65536 + 2 * 163840); // 256 B
    unsigned char* mark = (unsigned char*)(base2 + 3 * 65536 + 2 * 163840 + 4096); // 40,000 B
    int2*  edata    = (int2*)(base2 + 3 * 65536 + 2 * 163840 + 4096 + 40960);

    const int SCAN_BLOCKS = (NUM_NODE + 1023) / 1024;  // 40

    // ---- CSR build + bf16 convert ----
    hipMemsetAsync(cnt, 0, NUM_NODE * sizeof(int), stream);
    f2bf_hist_kernel<<<(NUM_NODE * DIM / 4 + 255) / 256, 256, 0, stream>>>(
        emb, embh, arows, cnt);
    scan1_kernel<<<SCAN_BLOCKS, 1024, 0, stream>>>(cnt, rowst, bsum, mark);
    scan2_kernel<<<1, 64, 0, stream>>>(bsum, SCAN_BLOCKS);
    scan3_kernel<<<SCAN_BLOCKS, 1024, 0, stream>>>(rowst, bsum);
    scatter_mark_kernel<<<(NEDGE + 255) / 256, 256, 0, stream>>>(
        arows, acols, avals, rowst, edata, sess_item, mark);

    // ---- inter: layer 1 full, layer 2 restricted to consumed rows ----
    const int prop_blocks = (NUM_NODE * 25 + 255) / 256;   // 3907
    csr_spmm_bf16_kernel<<<prop_blocks, 256, 0, stream>>>(rowst, edata, embh, y1);
    csr_spmm_bf16_masked_kernel<<<prop_blocks, 256, 0, stream>>>(rowst, edata, y1, y2, mark);

    // ---- session chain (3 kernels) ----
    sess_da_kernel<<<2 * NBATCH, 128, 0, stream>>>(sess_item, emb, sess_len, Dm, Am, s, DA);
    sprop_kernel<<<NBATCH, 128, 0, stream>>>(DA, s, s1);
    sprop_final_kernel<<<NBATCH, 128, 0, stream>>>(DA, s, s1, out_sess);

    // ---- intra attention + fused inter-gather + final add ----
    intra_kernel<<<NBATCH * 4, 1024, 0, stream>>>(inputs, edge, sess_item,
                                                  emb, y1, y2, a0, a1, a2, a3, out);
}

// Round 6
// 198.519 us; speedup vs baseline: 10.2686x; 1.0155x over previous
//
#include <hip/hip_runtime.h>
#include <hip/hip_bf16.h>

#define NUM_NODE 40000
#define DIM 100
#define NBATCH 128
#define NSEQ 70
#define NEDGE 640000
#define LEAKY_ALPHA 0.2f
#define RPB 18    // intra rows per block (4 blocks per batch -> 2 blocks/CU)
#define HPAD 116  // LDS row stride (floats), 16B-aligned

__device__ __forceinline__ float bf2f(unsigned short u) {
    return __uint_as_float(((unsigned int)u) << 16);
}
__device__ __forceinline__ unsigned short f2bf(float f) {
    unsigned int u = __float_as_uint(f);
    return (unsigned short)((u + 0x7FFFu + ((u >> 16) & 1u)) >> 16);  // RNE
}

// ---------------- zero cnt (hipMemsetAsync on 160KB costs 41us; this ~2us) -----
__global__ __launch_bounds__(1024) void zero_cnt_kernel(int* __restrict__ cnt)
{
    int i = blockIdx.x * 1024 + threadIdx.x;
    if (i < NUM_NODE) cnt[i] = 0;
}

// ---------------- fused: fp32->bf16 convert (1M float4) + edge histogram -------
__global__ __launch_bounds__(256) void f2bf_hist_kernel(
    const float* __restrict__ in, unsigned short* __restrict__ out,
    const int* __restrict__ rows, int* __restrict__ cnt)
{
    int gid = blockIdx.x * 256 + threadIdx.x;
    if (gid < NUM_NODE * DIM / 4) {
        float4 v = reinterpret_cast<const float4*>(in)[gid];
        ushort4 o;
        o.x = f2bf(v.x); o.y = f2bf(v.y); o.z = f2bf(v.z); o.w = f2bf(v.w);
        reinterpret_cast<ushort4*>(out)[gid] = o;
    }
    if (gid < NEDGE) atomicAdd(&cnt[rows[gid]], 1);
}

// ---------------- hierarchical exclusive scan, pass 1 (+ zero mark array) ------
__global__ __launch_bounds__(1024) void scan1_kernel(const int* __restrict__ cnt,
                                                     int* __restrict__ row_start,
                                                     int* __restrict__ bsum,
                                                     unsigned char* __restrict__ mark)
{
    __shared__ int wsum[16];
    int tid = threadIdx.x;
    int i = blockIdx.x * 1024 + tid;
    if (i < NUM_NODE) mark[i] = 0;
    int v = (i < NUM_NODE) ? cnt[i] : 0;
    int lane = tid & 63, wid = tid >> 6;
    int x = v;
    #pragma unroll
    for (int off = 1; off < 64; off <<= 1) {
        int t = __shfl_up(x, off, 64);
        if (lane >= off) x += t;
    }
    if (lane == 63) wsum[wid] = x;
    __syncthreads();
    if (wid == 0) {
        int w = (lane < 16) ? wsum[lane] : 0;
        #pragma unroll
        for (int off = 1; off < 16; off <<= 1) {
            int t = __shfl_up(w, off, 64);
            if (lane >= off) w += t;
        }
        if (lane < 16) wsum[lane] = w;
    }
    __syncthreads();
    int base = (wid > 0) ? wsum[wid - 1] : 0;
    int incl = base + x;
    if (i < NUM_NODE) row_start[i] = incl - v;   // exclusive
    if (tid == 1023) bsum[blockIdx.x] = incl;    // block total
}

// ---------------- pass 2: exclusive scan of 40 block sums (one wave) -----------
__global__ void scan2_kernel(int* __restrict__ bsum, int nblocks)
{
    int lane = threadIdx.x;
    int v = (lane < nblocks) ? bsum[lane] : 0;
    int x = v;
    #pragma unroll
    for (int off = 1; off < 64; off <<= 1) {
        int t = __shfl_up(x, off, 64);
        if (lane >= off) x += t;
    }
    if (lane < nblocks) bsum[lane] = x - v;      // exclusive
}

// ---------------- pass 3: add block offsets  ∥  sess gather-mean + DA=D@A ------
// blocks [0,40): scan offsets. blocks [40,72): 256 tasks x 128 threads.
__global__ __launch_bounds__(1024) void scan3_sess_da_kernel(
    int* __restrict__ row_start, const int* __restrict__ bsum,
    const int* __restrict__ sess_item, const float* __restrict__ emb,
    const float* __restrict__ sess_len,
    const float* __restrict__ Dm, const float* __restrict__ Am,
    float* __restrict__ s, float* __restrict__ DA)
{
    int blk = blockIdx.x;
    if (blk < 40) {
        int i = blk * 1024 + threadIdx.x;
        if (i < NUM_NODE) row_start[i] += bsum[blk];
        return;
    }
    int idx = (blk - 40) * 1024 + threadIdx.x;
    int task = idx >> 7, t = idx & 127;
    if (task < NBATCH) {
        if (t >= DIM) return;
        float acc = 0.f;
        for (int n = 0; n < NSEQ; ++n) {
            int r = sess_item[task * NSEQ + n];
            if (r > 0) acc += emb[(size_t)(r - 1) * DIM + t];
        }
        s[task * DIM + t] = acc / sess_len[task];
    } else if (task < 2 * NBATCH) {
        int i = task - NBATCH;
        float acc = 0.f;
        for (int k = 0; k < NBATCH; ++k) acc += Dm[i * NBATCH + k] * Am[k * NBATCH + t];
        DA[i * NBATCH + t] = acc;
    }
}

// ---------------- scatter (row_start -> row END) + mark needed output rows -----
__global__ __launch_bounds__(256) void scatter_mark_kernel(
    const int* __restrict__ rows, const int* __restrict__ cols,
    const float* __restrict__ vals, int* __restrict__ row_start,
    int2* __restrict__ edge_data,
    const int* __restrict__ sess_item, unsigned char* __restrict__ mark)
{
    int gid = blockIdx.x * 256 + threadIdx.x;
    if (gid < NBATCH * NSEQ) {
        int r = sess_item[gid];
        if (r > 0) mark[r - 1] = 1;      // benign same-value race
    }
    if (gid >= NEDGE) return;
    int r = rows[gid];
    int pos = atomicAdd(&row_start[r], 1);
    edge_data[pos] = make_int2(cols[gid], __float_as_int(vals[gid]));
}

#define SPMM_BLOCKS 3907   // ceil(NUM_NODE*25 / 256)
#define SESS_TAIL 50       // ceil(NBATCH*DIM / 256)

// ---------------- CSR SpMM bf16 layer 1 (all rows)  ∥  s1 = DA @ s -------------
__global__ __launch_bounds__(256) void spmm1_sprop_kernel(
    const int* __restrict__ row_start, const int2* __restrict__ edge_data,
    const unsigned short* __restrict__ x, unsigned short* __restrict__ y,
    const float* __restrict__ DA, const float* __restrict__ s,
    float* __restrict__ s1)
{
    if (blockIdx.x >= SPMM_BLOCKS) {
        int idx = (blockIdx.x - SPMM_BLOCKS) * 256 + threadIdx.x;
        int i = idx / DIM, d = idx - i * DIM;
        if (i >= NBATCH) return;
        float acc = 0.f;
        for (int k = 0; k < NBATCH; ++k) acc += DA[i * NBATCH + k] * s[k * DIM + d];
        s1[i * DIM + d] = acc;
        return;
    }
    int gid = blockIdx.x * 256 + threadIdx.x;   // NUM_NODE*25 = 1,000,000
    int r = gid / 25;
    int c = gid - r * 25;
    if (r >= NUM_NODE) return;
    int s0 = (r > 0) ? row_start[r - 1] : 0;
    int se = row_start[r];
    float a0 = 0.f, a1 = 0.f, a2 = 0.f, a3 = 0.f;
    for (int e = s0; e < se; ++e) {
        int2 ed = edge_data[e];
        float v = __int_as_float(ed.y);
        ushort4 xv = *reinterpret_cast<const ushort4*>(x + (size_t)ed.x * DIM + c * 4);
        a0 += v * bf2f(xv.x);
        a1 += v * bf2f(xv.y);
        a2 += v * bf2f(xv.z);
        a3 += v * bf2f(xv.w);
    }
    ushort4 o;
    o.x = f2bf(a0); o.y = f2bf(a1); o.z = f2bf(a2); o.w = f2bf(a3);
    *reinterpret_cast<ushort4*>(y + (size_t)r * DIM + c * 4) = o;
}

// ---------- CSR SpMM bf16 layer 2 (marked rows)  ∥  s2 = DA@s1; out_sess -------
__global__ __launch_bounds__(256) void spmm2_final_kernel(
    const int* __restrict__ row_start, const int2* __restrict__ edge_data,
    const unsigned short* __restrict__ x, unsigned short* __restrict__ y,
    const unsigned char* __restrict__ mark,
    const float* __restrict__ DA, const float* __restrict__ s,
    const float* __restrict__ s1, float* __restrict__ out2)
{
    if (blockIdx.x >= SPMM_BLOCKS) {
        int idx = (blockIdx.x - SPMM_BLOCKS) * 256 + threadIdx.x;
        int i = idx / DIM, d = idx - i * DIM;
        if (i >= NBATCH) return;
        float acc = 0.f;
        for (int k = 0; k < NBATCH; ++k) acc += DA[i * NBATCH + k] * s1[k * DIM + d];
        int o = i * DIM + d;
        out2[o] = (s[o] + s1[o] + acc) * (1.f / 3.f);
        return;
    }
    int gid = blockIdx.x * 256 + threadIdx.x;
    int r = gid / 25;
    int c = gid - r * 25;
    if (r >= NUM_NODE || !mark[r]) return;
    int s0 = (r > 0) ? row_start[r - 1] : 0;
    int se = row_start[r];
    float a0 = 0.f, a1 = 0.f, a2 = 0.f, a3 = 0.f;
    for (int e = s0; e < se; ++e) {
        int2 ed = edge_data[e];
        float v = __int_as_float(ed.y);
        ushort4 xv = *reinterpret_cast<const ushort4*>(x + (size_t)ed.x * DIM + c * 4);
        a0 += v * bf2f(xv.x);
        a1 += v * bf2f(xv.y);
        a2 += v * bf2f(xv.z);
        a3 += v * bf2f(xv.w);
    }
    ushort4 o;
    o.x = f2bf(a0); o.y = f2bf(a1); o.z = f2bf(a2); o.w = f2bf(a3);
    *reinterpret_cast<ushort4*>(y + (size_t)r * DIM + c * 4) = o;
}

// ---------------- intra attention + final combine (2 blocks/CU) ----------------
// blockIdx.x = b*4 + q; rows i in [q*RPB, min(q*RPB+RPB, 70))
__global__ __launch_bounds__(1024) void intra_kernel(
    const int* __restrict__ inputs, const int* __restrict__ edge,
    const int* __restrict__ sess_item,
    const float* __restrict__ emb, const unsigned short* __restrict__ y1,
    const unsigned short* __restrict__ y2,
    const float* __restrict__ a0, const float* __restrict__ a1,
    const float* __restrict__ a2, const float* __restrict__ a3,
    float* __restrict__ out)
{
    __shared__ float h[NSEQ][HPAD];
    __shared__ float av[4][HPAD];
    __shared__ float al[RPB][NSEQ + 2];
    int b = blockIdx.x >> 2;
    int q = blockIdx.x & 3;
    int i0 = q * RPB;
    int nrows = (i0 + RPB <= NSEQ) ? RPB : (NSEQ - i0);
    int tid = threadIdx.x;

    for (int idx = tid; idx < NSEQ * DIM; idx += 1024) {
        int n = idx / DIM, d = idx - n * DIM;
        h[n][d] = emb[(size_t)inputs[b * NSEQ + n] * DIM + d];
    }
    if (tid < 4 * DIM) {
        int k = tid / DIM, d = tid - k * DIM;
        const float* ap = (k == 0) ? a0 : (k == 1) ? a1 : (k == 2) ? a2 : a3;
        av[k][d] = ap[d];
    }
    __syncthreads();

    // phase A: selected logits via float4 LDS reads
    for (int p = tid; p < nrows * NSEQ; p += 1024) {
        int il = p / NSEQ, j = p - il * NSEQ;
        int i = i0 + il;
        int em = edge[(size_t)b * NSEQ * NSEQ + i * NSEQ + j];
        float val = -9e15f;
        if (em >= 1 && em <= 4) {
            const float* hi = h[i];
            const float* hj = h[j];
            const float* a  = av[em - 1];
            float sx = 0.f, sy = 0.f, sz = 0.f, sw = 0.f;
            #pragma unroll
            for (int d = 0; d < DIM; d += 4) {
                float4 x1 = *reinterpret_cast<const float4*>(hi + d);
                float4 x2 = *reinterpret_cast<const float4*>(hj + d);
                float4 x3 = *reinterpret_cast<const float4*>(a + d);
                sx += x1.x * x2.x * x3.x;
                sy += x1.y * x2.y * x3.y;
                sz += x1.z * x2.z * x3.z;
                sw += x1.w * x2.w * x3.w;
            }
            float sd = (sx + sy) + (sz + sw);
            val = sd >= 0.f ? sd : LEAKY_ALPHA * sd;
        }
        al[il][j] = val;
    }
    __syncthreads();

    // phase B: wave-parallel row softmax
    int wid = tid >> 6, lane = tid & 63;
    for (int row = wid; row < nrows; row += 16) {
        float v0 = (lane < NSEQ) ? al[row][lane] : -INFINITY;
        float v1 = (lane + 64 < NSEQ) ? al[row][lane + 64] : -INFINITY;
        float m = fmaxf(v0, v1);
        #pragma unroll
        for (int off = 32; off >= 1; off >>= 1) m = fmaxf(m, __shfl_xor(m, off, 64));
        float e0 = (lane < NSEQ) ? __expf(v0 - m) : 0.f;
        float e1 = (lane + 64 < NSEQ) ? __expf(v1 - m) : 0.f;
        float ssum = e0 + e1;
        #pragma unroll
        for (int off = 32; off >= 1; off >>= 1) ssum += __shfl_xor(ssum, off, 64);
        float inv = 1.f / ssum;
        if (lane < NSEQ) al[row][lane] = e0 * inv;
        if (lane + 64 < NSEQ) al[row][lane + 64] = e1 * inv;
    }
    __syncthreads();

    // phase C: out = alpha@h + inter_pad gather
    if (tid < nrows * 25) {
        int il = tid / 25, dc = (tid - il * 25) * 4;
        int i = i0 + il;
        float4 acc = make_float4(0.f, 0.f, 0.f, 0.f);
        for (int j = 0; j < NSEQ; ++j) {
            float w = al[il][j];
            float4 hv = *reinterpret_cast<const float4*>(&h[j][dc]);
            acc.x += w * hv.x;
            acc.y += w * hv.y;
            acc.z += w * hv.z;
            acc.w += w * hv.w;
        }
        int r = sess_item[b * NSEQ + i];
        if (r > 0) {
            size_t o = (size_t)(r - 1) * DIM + dc;
            float4 ev = *reinterpret_cast<const float4*>(emb + o);
            ushort4 u1 = *reinterpret_cast<const ushort4*>(y1 + o);
            ushort4 u2 = *reinterpret_cast<const ushort4*>(y2 + o);
            acc.x += (ev.x + bf2f(u1.x) + bf2f(u2.x)) * (1.f / 3.f);
            acc.y += (ev.y + bf2f(u1.y) + bf2f(u2.y)) * (1.f / 3.f);
            acc.z += (ev.z + bf2f(u1.z) + bf2f(u2.z)) * (1.f / 3.f);
            acc.w += (ev.w + bf2f(u1.w) + bf2f(u2.w)) * (1.f / 3.f);
        }
        *reinterpret_cast<float4*>(out + (size_t)b * NSEQ * DIM + (size_t)i * DIM + dc) = acc;
    }
}

extern "C" void kernel_launch(void* const* d_in, const int* in_sizes, int n_in,
                              void* d_out, int out_size, void* d_ws, size_t ws_size,
                              hipStream_t stream) {
    const int*   inputs    = (const int*)d_in[0];
    const int*   edge      = (const int*)d_in[1];
    // d_in[2] mask: unused; d_in[3] reversed_sess_item: unused
    const int*   sess_item = (const int*)d_in[4];
    const float* Dm        = (const float*)d_in[5];
    const float* Am        = (const float*)d_in[6];
    const float* sess_len  = (const float*)d_in[7];
    const float* emb       = (const float*)d_in[8];
    const float* a0        = (const float*)d_in[9];
    const float* a1        = (const float*)d_in[10];
    const float* a2        = (const float*)d_in[11];
    const float* a3        = (const float*)d_in[12];
    const int*   arows     = (const int*)d_in[13];
    const int*   acols     = (const int*)d_in[14];
    const float* avals     = (const float*)d_in[15];

    float* out      = (float*)d_out;                     // [B,N,D] = 896000
    float* out_sess = out + (size_t)NBATCH * NSEQ * DIM; // [B,D]   = 12800

    const size_t MATB = (size_t)NUM_NODE * DIM * sizeof(unsigned short); // 8,000,000 B
    char* ws = (char*)d_ws;
    unsigned short* embh = (unsigned short*)ws;
    unsigned short* y1   = (unsigned short*)(ws + MATB);
    unsigned short* y2   = (unsigned short*)(ws + 2 * MATB);
    char*  base2 = ws + 3 * MATB;
    float* s        = (float*)(base2 + 0);
    float* DA       = (float*)(base2 + 65536);
    float* s1       = (float*)(base2 + 2 * 65536);
    int*   cnt      = (int*)(base2 + 3 * 65536);              // 160,000 B
    int*   rowst    = (int*)(base2 + 3 * 65536 + 163840);     // 160,000 B
    int*   bsum     = (int*)(base2 + 3 * 65536 + 2 * 163840); // 256 B
    unsigned char* mark = (unsigned char*)(base2 + 3 * 65536 + 2 * 163840 + 4096); // 40,000 B
    int2*  edata    = (int2*)(base2 + 3 * 65536 + 2 * 163840 + 4096 + 40960);

    const int SCAN_BLOCKS = (NUM_NODE + 1023) / 1024;  // 40

    // ---- CSR build + bf16 convert ----
    zero_cnt_kernel<<<SCAN_BLOCKS, 1024, 0, stream>>>(cnt);
    f2bf_hist_kernel<<<(NUM_NODE * DIM / 4 + 255) / 256, 256, 0, stream>>>(
        emb, embh, arows, cnt);
    scan1_kernel<<<SCAN_BLOCKS, 1024, 0, stream>>>(cnt, rowst, bsum, mark);
    scan2_kernel<<<1, 64, 0, stream>>>(bsum, SCAN_BLOCKS);
    scan3_sess_da_kernel<<<SCAN_BLOCKS + 32, 1024, 0, stream>>>(
        rowst, bsum, sess_item, emb, sess_len, Dm, Am, s, DA);
    scatter_mark_kernel<<<(NEDGE + 255) / 256, 256, 0, stream>>>(
        arows, acols, avals, rowst, edata, sess_item, mark);

    // ---- inter layer 1 (all rows) ∥ s1 = DA@s ----
    spmm1_sprop_kernel<<<SPMM_BLOCKS + SESS_TAIL, 256, 0, stream>>>(
        rowst, edata, embh, y1, DA, s, s1);
    // ---- inter layer 2 (marked rows) ∥ s2 = DA@s1 + out_sess ----
    spmm2_final_kernel<<<SPMM_BLOCKS + SESS_TAIL, 256, 0, stream>>>(
        rowst, edata, y1, y2, mark, DA, s, s1, out_sess);

    // ---- intra attention + fused inter-gather + final add ----
    intra_kernel<<<NBATCH * 4, 1024, 0, stream>>>(inputs, edge, sess_item,
                                                  emb, y1, y2, a0, a1, a2, a3, out);
}

// Round 8
// 160.237 us; speedup vs baseline: 12.7219x; 1.2389x over previous
//
#include <hip/hip_runtime.h>
#include <hip/hip_bf16.h>

#define NUM_NODE 40000
#define DIM 100
#define NBATCH 128
#define NSEQ 70
#define NEDGE 640000
#define LEAKY_ALPHA 0.2f
#define RPB 18      // intra rows per block (4 blocks per batch)
#define CAP 64      // bucket capacity per node (deg ~ Poisson(16); P(>64) ~ 1e-26)
#define HB 52       // LDS row stride in uints (50 data + 2 pad; multiple of 4 for uint4)

__device__ __forceinline__ float bf2f(unsigned short u) {
    return __uint_as_float(((unsigned int)u) << 16);
}
__device__ __forceinline__ unsigned short f2bf(float f) {
    unsigned int u = __float_as_uint(f);
    return (unsigned short)((u + 0x7FFFu + ((u >> 16) & 1u)) >> 16);  // RNE
}
__device__ __forceinline__ float lo16(unsigned int u) { return __uint_as_float(u << 16); }
__device__ __forceinline__ float hi16(unsigned int u) { return __uint_as_float(u & 0xffff0000u); }

// ---------------- init: zero cnt[40000] + mark[40000 B] ----------------
__global__ __launch_bounds__(1024) void init_kernel(int* __restrict__ cnt,
                                                    int* __restrict__ mark_i)
{
    int i = blockIdx.x * 1024 + threadIdx.x;
    if (i < NUM_NODE) cnt[i] = 0;
    if (i < NUM_NODE / 4) mark_i[i] = 0;
}

// BUILD_BLOCKS must cover the LARGEST fused task: f2bf needs NUM_NODE*DIM/4 =
// 1,000,000 threads (round-7 bug: was sized to NEDGE=640k -> embh rows >=25600
// never written -> absmax 2.7e-2).
#define BUILD_BLOCKS 3907   // ceil(1,000,000 / 256)

// ------- build: f2bf(emb) + bucket-scatter(edges) + mark(sess) + sess-mean + DA
__global__ __launch_bounds__(256) void build_kernel(
    const float* __restrict__ emb, unsigned short* __restrict__ embh,
    const int* __restrict__ rows, const int* __restrict__ cols,
    const float* __restrict__ vals, int* __restrict__ cnt,
    int2* __restrict__ edata,
    const int* __restrict__ sess_item, unsigned char* __restrict__ mark,
    const float* __restrict__ sess_len,
    const float* __restrict__ Dm, const float* __restrict__ Am,
    float* __restrict__ s, float* __restrict__ DA)
{
    if (blockIdx.x >= BUILD_BLOCKS) {
        // session tail: 256 tasks x 128 threads (2 tasks per block)
        int idx = (blockIdx.x - BUILD_BLOCKS) * 256 + threadIdx.x;
        int task = idx >> 7, t = idx & 127;
        if (task < NBATCH) {
            if (t >= DIM) return;
            float acc = 0.f;
            for (int n = 0; n < NSEQ; ++n) {
                int r = sess_item[task * NSEQ + n];
                if (r > 0) acc += emb[(size_t)(r - 1) * DIM + t];
            }
            s[task * DIM + t] = acc / sess_len[task];
        } else if (task < 2 * NBATCH) {
            int i = task - NBATCH;
            float acc = 0.f;
            for (int k = 0; k < NBATCH; ++k) acc += Dm[i * NBATCH + k] * Am[k * NBATCH + t];
            DA[i * NBATCH + t] = acc;
        }
        return;
    }
    int gid = blockIdx.x * 256 + threadIdx.x;
    if (gid < NUM_NODE * DIM / 4) {        // f2bf: 1,000,000 float4 groups
        float4 v = reinterpret_cast<const float4*>(emb)[gid];
        ushort4 o;
        o.x = f2bf(v.x); o.y = f2bf(v.y); o.z = f2bf(v.z); o.w = f2bf(v.w);
        reinterpret_cast<ushort4*>(embh)[gid] = o;
    }
    if (gid < NBATCH * NSEQ) {             // mark rows consumed downstream
        int r = sess_item[gid];
        if (r > 0) mark[r - 1] = 1;        // benign same-value race
    }
    if (gid < NEDGE) {                     // bucket scatter
        int r = rows[gid];
        int pos = atomicAdd(&cnt[r], 1);
        if (pos < CAP) edata[(size_t)r * CAP + pos] =
            make_int2(cols[gid], __float_as_int(vals[gid]));
    }
}

#define SPMM_BLOCKS 3907   // ceil(NUM_NODE*25 / 256)
#define SESS_TAIL 50       // ceil(NBATCH*DIM / 256)

// ---------------- SpMM bf16 layer 1 (all rows)  ∥  s1 = DA @ s -------------
__global__ __launch_bounds__(256) void spmm1_sprop_kernel(
    const int* __restrict__ cnt, const int2* __restrict__ edata,
    const unsigned short* __restrict__ x, unsigned short* __restrict__ y,
    const float* __restrict__ DA, const float* __restrict__ s,
    float* __restrict__ s1)
{
    if (blockIdx.x >= SPMM_BLOCKS) {
        int idx = (blockIdx.x - SPMM_BLOCKS) * 256 + threadIdx.x;
        int i = idx / DIM, d = idx - i * DIM;
        if (i >= NBATCH) return;
        float acc = 0.f;
        for (int k = 0; k < NBATCH; ++k) acc += DA[i * NBATCH + k] * s[k * DIM + d];
        s1[i * DIM + d] = acc;
        return;
    }
    int gid = blockIdx.x * 256 + threadIdx.x;   // NUM_NODE*25 = 1,000,000
    int r = gid / 25;
    int c = gid - r * 25;
    if (r >= NUM_NODE) return;
    int deg = cnt[r]; if (deg > CAP) deg = CAP;
    const int2* ep = edata + (size_t)r * CAP;
    float a0 = 0.f, a1 = 0.f, a2 = 0.f, a3 = 0.f;
    for (int e = 0; e < deg; ++e) {
        int2 ed = ep[e];
        float v = __int_as_float(ed.y);
        ushort4 xv = *reinterpret_cast<const ushort4*>(x + (size_t)ed.x * DIM + c * 4);
        a0 += v * bf2f(xv.x);
        a1 += v * bf2f(xv.y);
        a2 += v * bf2f(xv.z);
        a3 += v * bf2f(xv.w);
    }
    ushort4 o;
    o.x = f2bf(a0); o.y = f2bf(a1); o.z = f2bf(a2); o.w = f2bf(a3);
    *reinterpret_cast<ushort4*>(y + (size_t)r * DIM + c * 4) = o;
}

// -------- SpMM bf16 layer 2 (marked rows)  ∥  s2 = DA@s1; out_sess ---------
__global__ __launch_bounds__(256) void spmm2_final_kernel(
    const int* __restrict__ cnt, const int2* __restrict__ edata,
    const unsigned short* __restrict__ x, unsigned short* __restrict__ y,
    const unsigned char* __restrict__ mark,
    const float* __restrict__ DA, const float* __restrict__ s,
    const float* __restrict__ s1, float* __restrict__ out2)
{
    if (blockIdx.x >= SPMM_BLOCKS) {
        int idx = (blockIdx.x - SPMM_BLOCKS) * 256 + threadIdx.x;
        int i = idx / DIM, d = idx - i * DIM;
        if (i >= NBATCH) return;
        float acc = 0.f;
        for (int k = 0; k < NBATCH; ++k) acc += DA[i * NBATCH + k] * s1[k * DIM + d];
        int o = i * DIM + d;
        out2[o] = (s[o] + s1[o] + acc) * (1.f / 3.f);
        return;
    }
    int gid = blockIdx.x * 256 + threadIdx.x;
    int r = gid / 25;
    int c = gid - r * 25;
    if (r >= NUM_NODE || !mark[r]) return;
    int deg = cnt[r]; if (deg > CAP) deg = CAP;
    const int2* ep = edata + (size_t)r * CAP;
    float a0 = 0.f, a1 = 0.f, a2 = 0.f, a3 = 0.f;
    for (int e = 0; e < deg; ++e) {
        int2 ed = ep[e];
        float v = __int_as_float(ed.y);
        ushort4 xv = *reinterpret_cast<const ushort4*>(x + (size_t)ed.x * DIM + c * 4);
        a0 += v * bf2f(xv.x);
        a1 += v * bf2f(xv.y);
        a2 += v * bf2f(xv.z);
        a3 += v * bf2f(xv.w);
    }
    ushort4 o;
    o.x = f2bf(a0); o.y = f2bf(a1); o.z = f2bf(a2); o.w = f2bf(a3);
    *reinterpret_cast<ushort4*>(y + (size_t)r * DIM + c * 4) = o;
}

// ---------------- intra attention + final combine (bf16 LDS) ----------------
// blockIdx.x = b*4 + q; rows i in [q*RPB, min(q*RPB+RPB, 70))
__global__ __launch_bounds__(1024) void intra_kernel(
    const int* __restrict__ inputs, const int* __restrict__ edge,
    const int* __restrict__ sess_item,
    const float* __restrict__ emb, const unsigned short* __restrict__ embh,
    const unsigned short* __restrict__ y1, const unsigned short* __restrict__ y2,
    const float* __restrict__ a0, const float* __restrict__ a1,
    const float* __restrict__ a2, const float* __restrict__ a3,
    float* __restrict__ out)
{
    __shared__ unsigned int hb[NSEQ][HB];    // packed bf16 x2 per uint
    __shared__ unsigned int avb[4][HB];
    __shared__ float al[RPB][NSEQ + 2];
    int b = blockIdx.x >> 2;
    int q = blockIdx.x & 3;
    int i0 = q * RPB;
    int nrows = (i0 + RPB <= NSEQ) ? RPB : (NSEQ - i0);
    int tid = threadIdx.x;

    // stage h (bf16, 70 rows x 25 uint2) from embh
    for (int idx = tid; idx < NSEQ * 25; idx += 1024) {
        int n = idx / 25, p = idx - n * 25;
        const uint2* src = reinterpret_cast<const uint2*>(
            embh + (size_t)inputs[b * NSEQ + n] * DIM);
        reinterpret_cast<uint2*>(hb[n])[p] = src[p];
    }
    if (tid < 4 * 50) {     // pack a-vectors to bf16
        int k = tid / 50, u = tid - k * 50;
        const float* ap = (k == 0) ? a0 : (k == 1) ? a1 : (k == 2) ? a2 : a3;
        unsigned int lo = f2bf(ap[2 * u]);
        unsigned int hi = f2bf(ap[2 * u + 1]);
        avb[k][u] = lo | (hi << 16);
    }
    __syncthreads();

    // phase A: selected logits, packed-bf16 triple product
    for (int p = tid; p < nrows * NSEQ; p += 1024) {
        int il = p / NSEQ, j = p - il * NSEQ;
        int i = i0 + il;
        int em = edge[(size_t)b * NSEQ * NSEQ + i * NSEQ + j];
        float val = -9e15f;
        if (em >= 1 && em <= 4) {
            const unsigned int* hi_ = hb[i];
            const unsigned int* hj_ = hb[j];
            const unsigned int* ab_ = avb[em - 1];
            float s0 = 0.f, s1 = 0.f, s2 = 0.f, s3 = 0.f;
            #pragma unroll
            for (int u = 0; u < 48; u += 4) {
                uint4 x1 = *reinterpret_cast<const uint4*>(hi_ + u);
                uint4 x2 = *reinterpret_cast<const uint4*>(hj_ + u);
                uint4 x3 = *reinterpret_cast<const uint4*>(ab_ + u);
                s0 += lo16(x1.x) * lo16(x2.x) * lo16(x3.x);
                s1 += hi16(x1.x) * hi16(x2.x) * hi16(x3.x);
                s2 += lo16(x1.y) * lo16(x2.y) * lo16(x3.y);
                s3 += hi16(x1.y) * hi16(x2.y) * hi16(x3.y);
                s0 += lo16(x1.z) * lo16(x2.z) * lo16(x3.z);
                s1 += hi16(x1.z) * hi16(x2.z) * hi16(x3.z);
                s2 += lo16(x1.w) * lo16(x2.w) * lo16(x3.w);
                s3 += hi16(x1.w) * hi16(x2.w) * hi16(x3.w);
            }
            {   // tail dims 96..99 (uints 48,49)
                uint2 x1 = *reinterpret_cast<const uint2*>(hi_ + 48);
                uint2 x2 = *reinterpret_cast<const uint2*>(hj_ + 48);
                uint2 x3 = *reinterpret_cast<const uint2*>(ab_ + 48);
                s0 += lo16(x1.x) * lo16(x2.x) * lo16(x3.x);
                s1 += hi16(x1.x) * hi16(x2.x) * hi16(x3.x);
                s2 += lo16(x1.y) * lo16(x2.y) * lo16(x3.y);
                s3 += hi16(x1.y) * hi16(x2.y) * hi16(x3.y);
            }
            float sd = (s0 + s1) + (s2 + s3);
            val = sd >= 0.f ? sd : LEAKY_ALPHA * sd;
        }
        al[il][j] = val;
    }
    __syncthreads();

    // phase B: wave-parallel row softmax
    int wid = tid >> 6, lane = tid & 63;
    for (int row = wid; row < nrows; row += 16) {
        float v0 = (lane < NSEQ) ? al[row][lane] : -INFINITY;
        float v1 = (lane + 64 < NSEQ) ? al[row][lane + 64] : -INFINITY;
        float m = fmaxf(v0, v1);
        #pragma unroll
        for (int off = 32; off >= 1; off >>= 1) m = fmaxf(m, __shfl_xor(m, off, 64));
        float e0 = (lane < NSEQ) ? __expf(v0 - m) : 0.f;
        float e1 = (lane + 64 < NSEQ) ? __expf(v1 - m) : 0.f;
        float ssum = e0 + e1;
        #pragma unroll
        for (int off = 32; off >= 1; off >>= 1) ssum += __shfl_xor(ssum, off, 64);
        float inv = 1.f / ssum;
        if (lane < NSEQ) al[row][lane] = e0 * inv;
        if (lane + 64 < NSEQ) al[row][lane + 64] = e1 * inv;
    }
    __syncthreads();

    // phase C: out = alpha@h + inter_pad gather
    if (tid < nrows * 25) {
        int il = tid / 25, chunk = tid - il * 25;   // 4 dims per chunk
        int i = i0 + il;
        int u = chunk * 2;
        float4 acc = make_float4(0.f, 0.f, 0.f, 0.f);
        for (int j = 0; j < NSEQ; ++j) {
            float w = al[il][j];
            uint2 hv = *reinterpret_cast<const uint2*>(hb[j] + u);
            acc.x += w * lo16(hv.x);
            acc.y += w * hi16(hv.x);
            acc.z += w * lo16(hv.y);
            acc.w += w * hi16(hv.y);
        }
        int dc = chunk * 4;
        int r = sess_item[b * NSEQ + i];
        if (r > 0) {
            size_t o = (size_t)(r - 1) * DIM + dc;
            float4 ev = *reinterpret_cast<const float4*>(emb + o);
            ushort4 u1 = *reinterpret_cast<const ushort4*>(y1 + o);
            ushort4 u2 = *reinterpret_cast<const ushort4*>(y2 + o);
            acc.x += (ev.x + bf2f(u1.x) + bf2f(u2.x)) * (1.f / 3.f);
            acc.y += (ev.y + bf2f(u1.y) + bf2f(u2.y)) * (1.f / 3.f);
            acc.z += (ev.z + bf2f(u1.z) + bf2f(u2.z)) * (1.f / 3.f);
            acc.w += (ev.w + bf2f(u1.w) + bf2f(u2.w)) * (1.f / 3.f);
        }
        *reinterpret_cast<float4*>(out + (size_t)b * NSEQ * DIM + (size_t)i * DIM + dc) = acc;
    }
}

extern "C" void kernel_launch(void* const* d_in, const int* in_sizes, int n_in,
                              void* d_out, int out_size, void* d_ws, size_t ws_size,
                              hipStream_t stream) {
    const int*   inputs    = (const int*)d_in[0];
    const int*   edge      = (const int*)d_in[1];
    // d_in[2] mask: unused; d_in[3] reversed_sess_item: unused
    const int*   sess_item = (const int*)d_in[4];
    const float* Dm        = (const float*)d_in[5];
    const float* Am        = (const float*)d_in[6];
    const float* sess_len  = (const float*)d_in[7];
    const float* emb       = (const float*)d_in[8];
    const float* a0        = (const float*)d_in[9];
    const float* a1        = (const float*)d_in[10];
    const float* a2        = (const float*)d_in[11];
    const float* a3        = (const float*)d_in[12];
    const int*   arows     = (const int*)d_in[13];
    const int*   acols     = (const int*)d_in[14];
    const float* avals     = (const float*)d_in[15];

    float* out      = (float*)d_out;                     // [B,N,D] = 896000
    float* out_sess = out + (size_t)NBATCH * NSEQ * DIM; // [B,D]   = 12800

    const size_t MATB = (size_t)NUM_NODE * DIM * sizeof(unsigned short); // 8,000,000 B
    char* ws = (char*)d_ws;
    unsigned short* embh = (unsigned short*)ws;
    unsigned short* y1   = (unsigned short*)(ws + MATB);
    unsigned short* y2   = (unsigned short*)(ws + 2 * MATB);
    char*  base2 = ws + 3 * MATB;
    float* s        = (float*)(base2 + 0);
    float* DA       = (float*)(base2 + 65536);
    float* s1       = (float*)(base2 + 2 * 65536);
    int*   cnt      = (int*)(base2 + 3 * 65536);              // 160,000 B
    unsigned char* mark = (unsigned char*)(base2 + 3 * 65536 + 163840); // 40,000 B
    int2*  edata    = (int2*)(base2 + 3 * 65536 + 163840 + 40960);      // 20.48 MB

    // 1. zero cnt + mark
    init_kernel<<<(NUM_NODE + 1023) / 1024, 1024, 0, stream>>>(cnt, (int*)mark);

    // 2. f2bf + bucket scatter + mark + session-mean + DA (fused)
    build_kernel<<<BUILD_BLOCKS + 128, 256, 0, stream>>>(
        emb, embh, arows, acols, avals, cnt, edata,
        sess_item, mark, sess_len, Dm, Am, s, DA);

    // 3. inter layer 1 (all rows) ∥ s1 = DA@s
    spmm1_sprop_kernel<<<SPMM_BLOCKS + SESS_TAIL, 256, 0, stream>>>(
        cnt, edata, embh, y1, DA, s, s1);

    // 4. inter layer 2 (marked rows) ∥ s2 = DA@s1 + out_sess
    spmm2_final_kernel<<<SPMM_BLOCKS + SESS_TAIL, 256, 0, stream>>>(
        cnt, edata, y1, y2, mark, DA, s, s1, out_sess);

    // 5. intra attention + fused inter-gather + final add
    intra_kernel<<<NBATCH * 4, 1024, 0, stream>>>(inputs, edge, sess_item,
                                                  emb, embh, y1, y2, a0, a1, a2, a3, out);
}

// Round 9
// 147.724 us; speedup vs baseline: 13.7995x; 1.0847x over previous
//
#include <hip/hip_runtime.h>
#include <hip/hip_bf16.h>

#define NUM_NODE 40000
#define DIM 100
#define NBATCH 128
#define NSEQ 70
#define NEDGE 640000
#define LEAKY_ALPHA 0.2f
#define RPB 18      // intra rows per block (4 blocks per batch)
#define CAP 64      // bucket capacity per node (deg ~ Poisson(16); P(>64) ~ 1e-26)
#define HB 52       // LDS row stride in uints (50 data + 2 pad; multiple of 4 for uint4)
#define CNTSTRIDE 16  // one counter per 64B cache line (atomic same-line contention fix)

__device__ __forceinline__ float bf2f(unsigned short u) {
    return __uint_as_float(((unsigned int)u) << 16);
}
__device__ __forceinline__ unsigned short f2bf(float f) {
    unsigned int u = __float_as_uint(f);
    return (unsigned short)((u + 0x7FFFu + ((u >> 16) & 1u)) >> 16);  // RNE
}
__device__ __forceinline__ float lo16(unsigned int u) { return __uint_as_float(u << 16); }
__device__ __forceinline__ float hi16(unsigned int u) { return __uint_as_float(u & 0xffff0000u); }

#define F2BF_BLOCKS 3907   // ceil(NUM_NODE*DIM/4 / 256)

// ---- kernel 1: f2bf(emb) + zero padded-cnt (2.56MB) + zero mark (40KB) --------
// Streaming conversion lives HERE so the scatter kernel runs with a quiet L2.
__global__ __launch_bounds__(256) void f2bf_init_kernel(
    const float* __restrict__ emb, unsigned short* __restrict__ embh,
    float4* __restrict__ cntp_v4, int4* __restrict__ mark_v4)
{
    int gid = blockIdx.x * 256 + threadIdx.x;
    if (gid < NUM_NODE * DIM / 4) {        // 1,000,000 float4 groups
        float4 v = reinterpret_cast<const float4*>(emb)[gid];
        ushort4 o;
        o.x = f2bf(v.x); o.y = f2bf(v.y); o.z = f2bf(v.z); o.w = f2bf(v.w);
        reinterpret_cast<ushort4*>(embh)[gid] = o;
    }
    if (gid < NUM_NODE * CNTSTRIDE / 4)    // zero 2,560,000 B of padded counters
        cntp_v4[gid] = make_float4(0.f, 0.f, 0.f, 0.f);
    if (gid < NUM_NODE / 16)               // zero 40,000 B of mark
        mark_v4[gid] = make_int4(0, 0, 0, 0);
}

#define BUILD_BLOCKS 2500   // NEDGE / 256

// ---- kernel 2: bucket-scatter(edges) + mark(sess) + sess-mean + DA ------------
__global__ __launch_bounds__(256) void build_kernel(
    const float* __restrict__ emb,
    const int* __restrict__ rows, const int* __restrict__ cols,
    const float* __restrict__ vals, int* __restrict__ cntp,
    int2* __restrict__ edata,
    const int* __restrict__ sess_item, unsigned char* __restrict__ mark,
    const float* __restrict__ sess_len,
    const float* __restrict__ Dm, const float* __restrict__ Am,
    float* __restrict__ s, float* __restrict__ DA)
{
    if (blockIdx.x >= BUILD_BLOCKS) {
        // session tail: 256 tasks x 128 threads (2 tasks per block)
        int idx = (blockIdx.x - BUILD_BLOCKS) * 256 + threadIdx.x;
        int task = idx >> 7, t = idx & 127;
        if (task < NBATCH) {
            if (t >= DIM) return;
            float acc = 0.f;
            for (int n = 0; n < NSEQ; ++n) {
                int r = sess_item[task * NSEQ + n];
                if (r > 0) acc += emb[(size_t)(r - 1) * DIM + t];
            }
            s[task * DIM + t] = acc / sess_len[task];
        } else if (task < 2 * NBATCH) {
            int i = task - NBATCH;
            float acc = 0.f;
            for (int k = 0; k < NBATCH; ++k) acc += Dm[i * NBATCH + k] * Am[k * NBATCH + t];
            DA[i * NBATCH + t] = acc;
        }
        return;
    }
    int gid = blockIdx.x * 256 + threadIdx.x;
    if (gid < NBATCH * NSEQ) {             // mark rows consumed downstream
        int r = sess_item[gid];
        if (r > 0) mark[r - 1] = 1;        // benign same-value race
    }
    // bucket scatter (all 640,000 gids < BUILD_BLOCKS*256)
    int r = rows[gid];
    int pos = atomicAdd(&cntp[r * CNTSTRIDE], 1);
    if (pos < CAP) edata[(size_t)r * CAP + pos] =
        make_int2(cols[gid], __float_as_int(vals[gid]));
}

#define SPMM_BLOCKS 3907   // ceil(NUM_NODE*25 / 256)
#define SESS_TAIL 50       // ceil(NBATCH*DIM / 256)

// ---------------- SpMM bf16 layer 1 (all rows)  ∥  s1 = DA @ s -------------
__global__ __launch_bounds__(256) void spmm1_sprop_kernel(
    const int* __restrict__ cntp, const int2* __restrict__ edata,
    const unsigned short* __restrict__ x, unsigned short* __restrict__ y,
    const float* __restrict__ DA, const float* __restrict__ s,
    float* __restrict__ s1)
{
    if (blockIdx.x >= SPMM_BLOCKS) {
        int idx = (blockIdx.x - SPMM_BLOCKS) * 256 + threadIdx.x;
        int i = idx / DIM, d = idx - i * DIM;
        if (i >= NBATCH) return;
        float acc = 0.f;
        for (int k = 0; k < NBATCH; ++k) acc += DA[i * NBATCH + k] * s[k * DIM + d];
        s1[i * DIM + d] = acc;
        return;
    }
    int gid = blockIdx.x * 256 + threadIdx.x;   // NUM_NODE*25 = 1,000,000
    int r = gid / 25;
    int c = gid - r * 25;
    if (r >= NUM_NODE) return;
    int deg = cntp[r * CNTSTRIDE]; if (deg > CAP) deg = CAP;
    const int2* ep = edata + (size_t)r * CAP;
    float a0 = 0.f, a1 = 0.f, a2 = 0.f, a3 = 0.f;
    for (int e = 0; e < deg; ++e) {
        int2 ed = ep[e];
        float v = __int_as_float(ed.y);
        ushort4 xv = *reinterpret_cast<const ushort4*>(x + (size_t)ed.x * DIM + c * 4);
        a0 += v * bf2f(xv.x);
        a1 += v * bf2f(xv.y);
        a2 += v * bf2f(xv.z);
        a3 += v * bf2f(xv.w);
    }
    ushort4 o;
    o.x = f2bf(a0); o.y = f2bf(a1); o.z = f2bf(a2); o.w = f2bf(a3);
    *reinterpret_cast<ushort4*>(y + (size_t)r * DIM + c * 4) = o;
}

// -------- SpMM bf16 layer 2 (marked rows)  ∥  s2 = DA@s1; out_sess ---------
__global__ __launch_bounds__(256) void spmm2_final_kernel(
    const int* __restrict__ cntp, const int2* __restrict__ edata,
    const unsigned short* __restrict__ x, unsigned short* __restrict__ y,
    const unsigned char* __restrict__ mark,
    const float* __restrict__ DA, const float* __restrict__ s,
    const float* __restrict__ s1, float* __restrict__ out2)
{
    if (blockIdx.x >= SPMM_BLOCKS) {
        int idx = (blockIdx.x - SPMM_BLOCKS) * 256 + threadIdx.x;
        int i = idx / DIM, d = idx - i * DIM;
        if (i >= NBATCH) return;
        float acc = 0.f;
        for (int k = 0; k < NBATCH; ++k) acc += DA[i * NBATCH + k] * s1[k * DIM + d];
        int o = i * DIM + d;
        out2[o] = (s[o] + s1[o] + acc) * (1.f / 3.f);
        return;
    }
    int gid = blockIdx.x * 256 + threadIdx.x;
    int r = gid / 25;
    int c = gid - r * 25;
    if (r >= NUM_NODE || !mark[r]) return;
    int deg = cntp[r * CNTSTRIDE]; if (deg > CAP) deg = CAP;
    const int2* ep = edata + (size_t)r * CAP;
    float a0 = 0.f, a1 = 0.f, a2 = 0.f, a3 = 0.f;
    for (int e = 0; e < deg; ++e) {
        int2 ed = ep[e];
        float v = __int_as_float(ed.y);
        ushort4 xv = *reinterpret_cast<const ushort4*>(x + (size_t)ed.x * DIM + c * 4);
        a0 += v * bf2f(xv.x);
        a1 += v * bf2f(xv.y);
        a2 += v * bf2f(xv.z);
        a3 += v * bf2f(xv.w);
    }
    ushort4 o;
    o.x = f2bf(a0); o.y = f2bf(a1); o.z = f2bf(a2); o.w = f2bf(a3);
    *reinterpret_cast<ushort4*>(y + (size_t)r * DIM + c * 4) = o;
}

// ---------------- intra attention + final combine (bf16 LDS) ----------------
// blockIdx.x = b*4 + q; rows i in [q*RPB, min(q*RPB+RPB, 70))
__global__ __launch_bounds__(1024) void intra_kernel(
    const int* __restrict__ inputs, const int* __restrict__ edge,
    const int* __restrict__ sess_item,
    const float* __restrict__ emb, const unsigned short* __restrict__ embh,
    const unsigned short* __restrict__ y1, const unsigned short* __restrict__ y2,
    const float* __restrict__ a0, const float* __restrict__ a1,
    const float* __restrict__ a2, const float* __restrict__ a3,
    float* __restrict__ out)
{
    __shared__ unsigned int hb[NSEQ][HB];    // packed bf16 x2 per uint
    __shared__ unsigned int avb[4][HB];
    __shared__ float al[RPB][NSEQ + 2];
    int b = blockIdx.x >> 2;
    int q = blockIdx.x & 3;
    int i0 = q * RPB;
    int nrows = (i0 + RPB <= NSEQ) ? RPB : (NSEQ - i0);
    int tid = threadIdx.x;

    // stage h (bf16, 70 rows x 25 uint2) from embh
    for (int idx = tid; idx < NSEQ * 25; idx += 1024) {
        int n = idx / 25, p = idx - n * 25;
        const uint2* src = reinterpret_cast<const uint2*>(
            embh + (size_t)inputs[b * NSEQ + n] * DIM);
        reinterpret_cast<uint2*>(hb[n])[p] = src[p];
    }
    if (tid < 4 * 50) {     // pack a-vectors to bf16
        int k = tid / 50, u = tid - k * 50;
        const float* ap = (k == 0) ? a0 : (k == 1) ? a1 : (k == 2) ? a2 : a3;
        unsigned int lo = f2bf(ap[2 * u]);
        unsigned int hi = f2bf(ap[2 * u + 1]);
        avb[k][u] = lo | (hi << 16);
    }
    __syncthreads();

    // phase A: selected logits, packed-bf16 triple product
    for (int p = tid; p < nrows * NSEQ; p += 1024) {
        int il = p / NSEQ, j = p - il * NSEQ;
        int i = i0 + il;
        int em = edge[(size_t)b * NSEQ * NSEQ + i * NSEQ + j];
        float val = -9e15f;
        if (em >= 1 && em <= 4) {
            const unsigned int* hi_ = hb[i];
            const unsigned int* hj_ = hb[j];
            const unsigned int* ab_ = avb[em - 1];
            float s0 = 0.f, s1 = 0.f, s2 = 0.f, s3 = 0.f;
            #pragma unroll
            for (int u = 0; u < 48; u += 4) {
                uint4 x1 = *reinterpret_cast<const uint4*>(hi_ + u);
                uint4 x2 = *reinterpret_cast<const uint4*>(hj_ + u);
                uint4 x3 = *reinterpret_cast<const uint4*>(ab_ + u);
                s0 += lo16(x1.x) * lo16(x2.x) * lo16(x3.x);
                s1 += hi16(x1.x) * hi16(x2.x) * hi16(x3.x);
                s2 += lo16(x1.y) * lo16(x2.y) * lo16(x3.y);
                s3 += hi16(x1.y) * hi16(x2.y) * hi16(x3.y);
                s0 += lo16(x1.z) * lo16(x2.z) * lo16(x3.z);
                s1 += hi16(x1.z) * hi16(x2.z) * hi16(x3.z);
                s2 += lo16(x1.w) * lo16(x2.w) * lo16(x3.w);
                s3 += hi16(x1.w) * hi16(x2.w) * hi16(x3.w);
            }
            {   // tail dims 96..99 (uints 48,49)
                uint2 x1 = *reinterpret_cast<const uint2*>(hi_ + 48);
                uint2 x2 = *reinterpret_cast<const uint2*>(hj_ + 48);
                uint2 x3 = *reinterpret_cast<const uint2*>(ab_ + 48);
                s0 += lo16(x1.x) * lo16(x2.x) * lo16(x3.x);
                s1 += hi16(x1.x) * hi16(x2.x) * hi16(x3.x);
                s2 += lo16(x1.y) * lo16(x2.y) * lo16(x3.y);
                s3 += hi16(x1.y) * hi16(x2.y) * hi16(x3.y);
            }
            float sd = (s0 + s1) + (s2 + s3);
            val = sd >= 0.f ? sd : LEAKY_ALPHA * sd;
        }
        al[il][j] = val;
    }
    __syncthreads();

    // phase B: wave-parallel row softmax
    int wid = tid >> 6, lane = tid & 63;
    for (int row = wid; row < nrows; row += 16) {
        float v0 = (lane < NSEQ) ? al[row][lane] : -INFINITY;
        float v1 = (lane + 64 < NSEQ) ? al[row][lane + 64] : -INFINITY;
        float m = fmaxf(v0, v1);
        #pragma unroll
        for (int off = 32; off >= 1; off >>= 1) m = fmaxf(m, __shfl_xor(m, off, 64));
        float e0 = (lane < NSEQ) ? __expf(v0 - m) : 0.f;
        float e1 = (lane + 64 < NSEQ) ? __expf(v1 - m) : 0.f;
        float ssum = e0 + e1;
        #pragma unroll
        for (int off = 32; off >= 1; off >>= 1) ssum += __shfl_xor(ssum, off, 64);
        float inv = 1.f / ssum;
        if (lane < NSEQ) al[row][lane] = e0 * inv;
        if (lane + 64 < NSEQ) al[row][lane + 64] = e1 * inv;
    }
    __syncthreads();

    // phase C: out = alpha@h + inter_pad gather
    if (tid < nrows * 25) {
        int il = tid / 25, chunk = tid - il * 25;   // 4 dims per chunk
        int i = i0 + il;
        int u = chunk * 2;
        float4 acc = make_float4(0.f, 0.f, 0.f, 0.f);
        for (int j = 0; j < NSEQ; ++j) {
            float w = al[il][j];
            uint2 hv = *reinterpret_cast<const uint2*>(hb[j] + u);
            acc.x += w * lo16(hv.x);
            acc.y += w * hi16(hv.x);
            acc.z += w * lo16(hv.y);
            acc.w += w * hi16(hv.y);
        }
        int dc = chunk * 4;
        int r = sess_item[b * NSEQ + i];
        if (r > 0) {
            size_t o = (size_t)(r - 1) * DIM + dc;
            float4 ev = *reinterpret_cast<const float4*>(emb + o);
            ushort4 u1 = *reinterpret_cast<const ushort4*>(y1 + o);
            ushort4 u2 = *reinterpret_cast<const ushort4*>(y2 + o);
            acc.x += (ev.x + bf2f(u1.x) + bf2f(u2.x)) * (1.f / 3.f);
            acc.y += (ev.y + bf2f(u1.y) + bf2f(u2.y)) * (1.f / 3.f);
            acc.z += (ev.z + bf2f(u1.z) + bf2f(u2.z)) * (1.f / 3.f);
            acc.w += (ev.w + bf2f(u1.w) + bf2f(u2.w)) * (1.f / 3.f);
        }
        *reinterpret_cast<float4*>(out + (size_t)b * NSEQ * DIM + (size_t)i * DIM + dc) = acc;
    }
}

extern "C" void kernel_launch(void* const* d_in, const int* in_sizes, int n_in,
                              void* d_out, int out_size, void* d_ws, size_t ws_size,
                              hipStream_t stream) {
    const int*   inputs    = (const int*)d_in[0];
    const int*   edge      = (const int*)d_in[1];
    // d_in[2] mask: unused; d_in[3] reversed_sess_item: unused
    const int*   sess_item = (const int*)d_in[4];
    const float* Dm        = (const float*)d_in[5];
    const float* Am        = (const float*)d_in[6];
    const float* sess_len  = (const float*)d_in[7];
    const float* emb       = (const float*)d_in[8];
    const float* a0        = (const float*)d_in[9];
    const float* a1        = (const float*)d_in[10];
    const float* a2        = (const float*)d_in[11];
    const float* a3        = (const float*)d_in[12];
    const int*   arows     = (const int*)d_in[13];
    const int*   acols     = (const int*)d_in[14];
    const float* avals     = (const float*)d_in[15];

    float* out      = (float*)d_out;                     // [B,N,D] = 896000
    float* out_sess = out + (size_t)NBATCH * NSEQ * DIM; // [B,D]   = 12800

    const size_t MATB = (size_t)NUM_NODE * DIM * sizeof(unsigned short); // 8,000,000 B
    char* ws = (char*)d_ws;
    unsigned short* embh = (unsigned short*)ws;
    unsigned short* y1   = (unsigned short*)(ws + MATB);
    unsigned short* y2   = (unsigned short*)(ws + 2 * MATB);
    char*  base2 = ws + 3 * MATB;
    float* s        = (float*)(base2 + 0);
    float* DA       = (float*)(base2 + 65536);
    float* s1       = (float*)(base2 + 2 * 65536);
    int*   cntp     = (int*)(base2 + 3 * 65536);              // 2,560,000 B (padded)
    unsigned char* mark = (unsigned char*)(base2 + 3 * 65536 + 2560000); // 40,000 B
    int2*  edata    = (int2*)(base2 + 3 * 65536 + 2560000 + 40960);      // 20.48 MB

    // 1. f2bf + zero padded counters + zero mark
    f2bf_init_kernel<<<F2BF_BLOCKS, 256, 0, stream>>>(
        emb, embh, (float4*)cntp, (int4*)mark);

    // 2. bucket scatter + mark + session-mean + DA (quiet-L2 scatter)
    build_kernel<<<BUILD_BLOCKS + 128, 256, 0, stream>>>(
        emb, arows, acols, avals, cntp, edata,
        sess_item, mark, sess_len, Dm, Am, s, DA);

    // 3. inter layer 1 (all rows) ∥ s1 = DA@s
    spmm1_sprop_kernel<<<SPMM_BLOCKS + SESS_TAIL, 256, 0, stream>>>(
        cntp, edata, embh, y1, DA, s, s1);

    // 4. inter layer 2 (marked rows) ∥ s2 = DA@s1 + out_sess
    spmm2_final_kernel<<<SPMM_BLOCKS + SESS_TAIL, 256, 0, stream>>>(
        cntp, edata, y1, y2, mark, DA, s, s1, out_sess);

    // 5. intra attention + fused inter-gather + final add
    intra_kernel<<<NBATCH * 4, 1024, 0, stream>>>(inputs, edge, sess_item,
                                                  emb, embh, y1, y2, a0, a1, a2, a3, out);
}